// Round 3
// baseline (799.138 us; speedup 1.0000x reference)
//
#include <hip/hip_runtime.h>
#include <stdint.h>

typedef __attribute__((ext_vector_type(4))) float f32x4;
typedef _Float16 half8 __attribute__((ext_vector_type(8)));
typedef _Float16 half4 __attribute__((ext_vector_type(4)));

// ---------------- CSR build via bucket binning ----------------

#define BIN_CHUNK 8192   // edges per block, 32/thread
#define MAXB 512         // >= nb = ceil(N/256)

__global__ __launch_bounds__(256) void k_bhist(const int* __restrict__ dst,
                                               int* __restrict__ bcnt, int E) {
    __shared__ int lh[MAXB];
    for (int i = threadIdx.x; i < MAXB; i += 256) lh[i] = 0;
    __syncthreads();
    const int base = blockIdx.x * BIN_CHUNK;
#pragma unroll 4
    for (int i = 0; i < BIN_CHUNK / 256; i++) {
        int e = base + i * 256 + threadIdx.x;
        if (e < E) atomicAdd(&lh[dst[e] >> 8], 1);
    }
    __syncthreads();
    for (int i = threadIdx.x; i < MAXB; i += 256)
        if (lh[i]) atomicAdd(&bcnt[i], lh[i]);
}

__global__ void k_bscan(const int* __restrict__ bcnt, int* __restrict__ bbase,
                        int* __restrict__ gcur, int nb) {
    if (threadIdx.x == 0 && blockIdx.x == 0) {
        int run = 0;
        for (int i = 0; i < nb; i++) { bbase[i] = run; gcur[i] = run; run += bcnt[i]; }
        bbase[nb] = run;
    }
}

__global__ __launch_bounds__(256) void k_bin(const int* __restrict__ src,
                                             const int* __restrict__ dst,
                                             int* __restrict__ gcur,
                                             unsigned* __restrict__ ebuf, int E) {
    __shared__ int lh[MAXB];
    __shared__ int lcur[MAXB];
    for (int i = threadIdx.x; i < MAXB; i += 256) lh[i] = 0;
    __syncthreads();
    const int base = blockIdx.x * BIN_CHUNK;
#pragma unroll 4
    for (int i = 0; i < BIN_CHUNK / 256; i++) {
        int e = base + i * 256 + threadIdx.x;
        if (e < E) atomicAdd(&lh[dst[e] >> 8], 1);
    }
    __syncthreads();
    for (int i = threadIdx.x; i < MAXB; i += 256)
        lcur[i] = lh[i] ? atomicAdd(&gcur[i], lh[i]) : 0;
    __syncthreads();
#pragma unroll 4
    for (int i = 0; i < BIN_CHUNK / 256; i++) {
        int e = base + i * 256 + threadIdx.x;
        if (e < E) {
            int d = dst[e];
            int pos = atomicAdd(&lcur[d >> 8], 1);
            ebuf[pos] = (unsigned)src[e] | ((unsigned)(d & 255) << 24);
        }
    }
}

__global__ __launch_bounds__(256) void k_nhist(const unsigned* __restrict__ ebuf,
                                               const int* __restrict__ bbase,
                                               int* __restrict__ deg, int N) {
    __shared__ int cnt[256];
    cnt[threadIdx.x] = 0;
    __syncthreads();
    const int b = blockIdx.x;
    const int lo = bbase[b], hi = bbase[b + 1];
    for (int e = lo + threadIdx.x; e < hi; e += 256)
        atomicAdd(&cnt[ebuf[e] >> 24], 1);
    __syncthreads();
    int n = (b << 8) + threadIdx.x;
    if (n < N) deg[n] = cnt[threadIdx.x];
}

__global__ __launch_bounds__(256) void k_bfill(const unsigned* __restrict__ ebuf,
                                               const int* __restrict__ bbase,
                                               const int* __restrict__ rowptr,
                                               int* __restrict__ ssrc, int N) {
    __shared__ int lc[256];
    const int b = blockIdx.x;
    int n = (b << 8) + threadIdx.x;
    lc[threadIdx.x] = (n < N) ? rowptr[n] : 0;
    __syncthreads();
    const int lo = bbase[b], hi = bbase[b + 1];
    for (int e = lo + threadIdx.x; e < hi; e += 256) {
        unsigned v = ebuf[e];
        int pos = atomicAdd(&lc[v >> 24], 1);
        ssrc[pos] = (int)(v & 0xFFFFFFu);
    }
}

// ---------------- rowptr scan ----------------

__global__ void k_scan1(int* __restrict__ buf, int* __restrict__ chunkSum, int N) {
    const int t = threadIdx.x;
    const int base = blockIdx.x * 2048 + t * 8;
    int v[8];
    int s = 0;
#pragma unroll
    for (int i = 0; i < 8; i++) {
        int idx = base + i;
        v[i] = (idx < N) ? buf[idx] : 0;
        s += v[i];
    }
    __shared__ int sh[256];
    sh[t] = s;
    __syncthreads();
    for (int off = 1; off < 256; off <<= 1) {
        int add = (t >= off) ? sh[t - off] : 0;
        __syncthreads();
        sh[t] += add;
        __syncthreads();
    }
    int excl = sh[t] - s;
    int run = excl;
#pragma unroll
    for (int i = 0; i < 8; i++) {
        int idx = base + i;
        if (idx < N) buf[idx] = run;
        run += v[i];
    }
    if (t == 255) chunkSum[blockIdx.x] = sh[255];
}

__global__ void k_scan2(const int* __restrict__ chunkSum, int* __restrict__ chunkOff,
                        int nch, int* __restrict__ rowptrN) {
    if (threadIdx.x == 0 && blockIdx.x == 0) {
        int run = 0;
        for (int i = 0; i < nch; i++) { chunkOff[i] = run; run += chunkSum[i]; }
        *rowptrN = run;
    }
}

__global__ void k_scan3(int* __restrict__ rowptr, const int* __restrict__ chunkOff, int N) {
    int i = blockIdx.x * 256 + threadIdx.x;
    if (i < N) rowptr[i] += chunkOff[i >> 11];
}

// ---------------- weight prep: k-blocked layout ----------------

template <int K, int NCOLT>
__global__ void k_wprep(const float* __restrict__ Wl, const float* __restrict__ Wr,
                        _Float16* __restrict__ Wt) {
    constexpr int NCOL = NCOLT / 2;
    int i = blockIdx.x * 256 + threadIdx.x;
    if (i < K * NCOLT) {
        int n = i / K, k = i - n * K;
        float v = (n < NCOL) ? Wl[(size_t)k * NCOL + n] : Wr[(size_t)k * NCOL + (n - NCOL)];
        Wt[(size_t)(k >> 5) * (NCOLT * 32) + n * 32 + (k & 31)] = (_Float16)v;
    }
}

// ---------------- MFMA GEMM: [Cl|Cr] = A @ [Wl|Wr] ----------------

template <int K, int NCOLT, bool AF32>
__global__ __launch_bounds__(256) void k_gemmM(const void* __restrict__ Av,
                                               const _Float16* __restrict__ Wt,
                                               const float* __restrict__ bias,
                                               _Float16* __restrict__ Cl,
                                               _Float16* __restrict__ Cr, int M) {
    constexpr int NCOL = NCOLT / 2;
    constexpr int WC = NCOLT / 4;
    constexpr int NT = WC / 16;
    constexpr int AS = K + 8;
    constexpr int CS = NCOLT + 8;
    constexpr int MAXS = (K > NCOLT ? K : NCOLT) + 8;
    __shared__ _Float16 sh[64 * MAXS];

    const int tid = threadIdx.x;
    const int lane = tid & 63;
    const int wave = tid >> 6;
    const int quad = lane >> 4;
    const int l16 = lane & 15;
    const int m0 = blockIdx.x * 64;
    const int colbase = wave * WC;

    if (AF32) {
        const float* A = (const float*)Av;
#pragma unroll
        for (int i = 0; i < K / 16; i++) {
            int off = i * 1024 + tid * 4;
            int row = off / K, col = off % K;
            f32x4 u = {0.f, 0.f, 0.f, 0.f};
            if (m0 + row < M) u = *(const f32x4*)(A + (size_t)(m0 + row) * K + col);
            half4 h = {(_Float16)u[0], (_Float16)u[1], (_Float16)u[2], (_Float16)u[3]};
            *(half4*)(sh + row * AS + col) = h;
        }
    } else {
        const _Float16* A = (const _Float16*)Av;
#pragma unroll
        for (int i = 0; i < K / 32; i++) {
            int off = i * 2048 + tid * 8;
            int row = off / K, col = off % K;
            half8 u = {0, 0, 0, 0, 0, 0, 0, 0};
            if (m0 + row < M) u = *(const half8*)(A + (size_t)(m0 + row) * K + col);
            *(half8*)(sh + row * AS + col) = u;
        }
    }
    __syncthreads();

    f32x4 acc[4][NT];
#pragma unroll
    for (int rg = 0; rg < 4; rg++)
#pragma unroll
        for (int t = 0; t < NT; t++) acc[rg][t] = (f32x4){0.f, 0.f, 0.f, 0.f};

#pragma unroll
    for (int k0 = 0; k0 < K; k0 += 32) {
        half8 a[4];
#pragma unroll
        for (int rg = 0; rg < 4; rg++)
            a[rg] = *(const half8*)(sh + (rg * 16 + l16) * AS + k0 + quad * 8);
        half8 b[NT];
        const _Float16* Wk = Wt + (size_t)(k0 >> 5) * (NCOLT * 32);
#pragma unroll
        for (int t = 0; t < NT; t++)
            b[t] = *(const half8*)(Wk + (colbase + t * 16 + l16) * 32 + quad * 8);
#pragma unroll
        for (int rg = 0; rg < 4; rg++)
#pragma unroll
            for (int t = 0; t < NT; t++)
                acc[rg][t] = __builtin_amdgcn_mfma_f32_16x16x32_f16(b[t], a[rg], acc[rg][t], 0, 0, 0);
    }

    __syncthreads();

#pragma unroll
    for (int t = 0; t < NT; t++) {
        int c0 = colbase + t * 16 + quad * 4;
        f32x4 bv = {0.f, 0.f, 0.f, 0.f};
        if (c0 >= NCOL) bv = *(const f32x4*)(bias + (c0 - NCOL));
#pragma unroll
        for (int rg = 0; rg < 4; rg++) {
            half4 h = {(_Float16)(acc[rg][t][0] + bv[0]), (_Float16)(acc[rg][t][1] + bv[1]),
                       (_Float16)(acc[rg][t][2] + bv[2]), (_Float16)(acc[rg][t][3] + bv[3])};
            *(half4*)(sh + (rg * 16 + l16) * CS + c0) = h;
        }
    }
    __syncthreads();

#pragma unroll
    for (int i = 0; i < (64 * NCOL) / 2048; i++) {
        int off = i * 2048 + tid * 8;
        int row = off / NCOL, col = off % NCOL;
        if (m0 + row < M) {
            *(half8*)(Cl + (size_t)(m0 + row) * NCOL + col) = *(const half8*)(sh + row * CS + col);
            *(half8*)(Cr + (size_t)(m0 + row) * NCOL + col) = *(const half8*)(sh + row * CS + NCOL + col);
        }
    }
}

// ---------------- aggregation: block-balanced edge-parallel ----------------
// Block owns NB contiguous nodes; its edge range [rowptr[n0], rowptr[n0+NB]) is
// contiguous in ssrc. That range is split EVENLY across lane-groups (16 ch each),
// independent of node boundaries -> no degree-tail divergence. Groups register-
// accumulate runs of same-dst edges, flush to padded f32 LDS acc via atomicAdd
// at node boundaries (~2 flushes/slice). Phase 3 applies mean+xr and stores.

template <int COUT, int MODE>
__global__ __launch_bounds__(256) void k_agg(const _Float16* __restrict__ xl,
                                             const _Float16* __restrict__ xr,
                                             const int* __restrict__ rowptr,
                                             const int* __restrict__ ssrc,
                                             float* __restrict__ outF1,
                                             float* __restrict__ outF2,
                                             _Float16* __restrict__ outH, int N) {
    constexpr int LPN = COUT / 16;   // lanes covering one row's channels: 8 / 4
    constexpr int NB = 256 / LPN;    // nodes per block: 32 / 64
    constexpr int AP = COUT + 4;     // padded LDS row stride (floats)
    __shared__ float acc[NB * AP];
    __shared__ int rp[NB + 1];

    const int tid = threadIdx.x;
    const int n0 = blockIdx.x * NB;
    if (tid <= NB) {
        int nn = n0 + tid;
        rp[tid] = rowptr[nn < N ? nn : N];
    }
    for (int i = tid; i < NB * AP; i += 256) acc[i] = 0.f;
    __syncthreads();

    const int lo = rp[0];
    const int B = rp[NB] - lo;
    const int g = tid / LPN;     // group id 0..NB-1
    const int c = tid % LPN;
    const int cb = c * 16;

    int e0 = lo + (int)(((long long)B * g) / NB);
    int e1 = lo + (int)(((long long)B * (g + 1)) / NB);

    if (e0 < e1) {
        // find j with rp[j] <= e0 < rp[j+1]
        int jl = 0, jh = NB - 1;
        while (jl < jh) {
            int mid = (jl + jh) >> 1;
            if (rp[mid + 1] <= e0) jl = mid + 1; else jh = mid;
        }
        int j = jl;
        float racc[16];
#pragma unroll
        for (int i = 0; i < 16; i++) racc[i] = 0.f;

        int e = e0;
        while (e < e1) {
            int ee = rp[j + 1];
            if (ee > e1) ee = e1;
            for (; e + 3 < ee; e += 4) {
                int s0 = ssrc[e], s1 = ssrc[e + 1], s2 = ssrc[e + 2], s3 = ssrc[e + 3];
                const half8* p0 = (const half8*)(xl + (size_t)s0 * COUT + cb);
                const half8* p1 = (const half8*)(xl + (size_t)s1 * COUT + cb);
                const half8* p2 = (const half8*)(xl + (size_t)s2 * COUT + cb);
                const half8* p3 = (const half8*)(xl + (size_t)s3 * COUT + cb);
                half8 v0a = p0[0], v0b = p0[1];
                half8 v1a = p1[0], v1b = p1[1];
                half8 v2a = p2[0], v2b = p2[1];
                half8 v3a = p3[0], v3b = p3[1];
#pragma unroll
                for (int i = 0; i < 8; i++) {
                    racc[i] += (float)v0a[i] + (float)v1a[i] + (float)v2a[i] + (float)v3a[i];
                    racc[8 + i] += (float)v0b[i] + (float)v1b[i] + (float)v2b[i] + (float)v3b[i];
                }
            }
            for (; e < ee; e++) {
                int s = ssrc[e];
                const half8* p = (const half8*)(xl + (size_t)s * COUT + cb);
                half8 va = p[0], vb = p[1];
#pragma unroll
                for (int i = 0; i < 8; i++) {
                    racc[i] += (float)va[i];
                    racc[8 + i] += (float)vb[i];
                }
            }
            // node j done (or slice ended): flush
#pragma unroll
            for (int i = 0; i < 16; i++) {
                atomicAdd(&acc[j * AP + cb + i], racc[i]);
                racc[i] = 0.f;
            }
            while (j < NB - 1 && rp[j + 1] <= e) j++;
        }
    }
    __syncthreads();

    // ---- phase 3: mean + xr, store ----
    const int node = tid / LPN;
    const int n = n0 + node;
    if (n >= N) return;
    const int deg = rp[node + 1] - rp[node];
    const float scale = 1.0f / (float)(deg > 1 ? deg : 1);
    const half8* xp = (const half8*)(xr + (size_t)n * COUT + cb);
    half8 x0 = xp[0], x1 = xp[1];
    float res[16];
#pragma unroll
    for (int i = 0; i < 8; i++) {
        res[i] = acc[node * AP + cb + i] * scale + (float)x0[i];
        res[8 + i] = acc[node * AP + cb + 8 + i] * scale + (float)x1[i];
    }

    const size_t ob = (size_t)n * COUT + cb;
    if (MODE == 0) {
        half8 h0v, h1v;
#pragma unroll
        for (int i = 0; i < 8; i++) {
            h0v[i] = (_Float16)(res[i] > 0.f ? res[i] : 0.f);
            h1v[i] = (_Float16)(res[8 + i] > 0.f ? res[8 + i] : 0.f);
        }
        *(half8*)(outH + ob) = h0v;
        *(half8*)(outH + ob + 8) = h1v;
    } else if (MODE == 1) {
#pragma unroll
        for (int q = 0; q < 4; q++) {
            f32x4 v = {res[q * 4], res[q * 4 + 1], res[q * 4 + 2], res[q * 4 + 3]};
            *(f32x4*)(outF1 + ob + q * 4) = v;
            f32x4 z = {v[0] > 0.f ? v[0] : 0.f, v[1] > 0.f ? v[1] : 0.f,
                       v[2] > 0.f ? v[2] : 0.f, v[3] > 0.f ? v[3] : 0.f};
            *(f32x4*)(outF2 + ob + q * 4) = z;
        }
        half8 h0v, h1v;
#pragma unroll
        for (int i = 0; i < 8; i++) {
            h0v[i] = (_Float16)(res[i] > 0.f ? res[i] : 0.f);
            h1v[i] = (_Float16)(res[8 + i] > 0.f ? res[8 + i] : 0.f);
        }
        *(half8*)(outH + ob) = h0v;
        *(half8*)(outH + ob + 8) = h1v;
    } else {
#pragma unroll
        for (int q = 0; q < 4; q++) {
            f32x4 v = {res[q * 4], res[q * 4 + 1], res[q * 4 + 2], res[q * 4 + 3]};
            *(f32x4*)(outF1 + ob + q * 4) = v;
        }
    }
}

// ---------------- launch ----------------

extern "C" void kernel_launch(void* const* d_in, const int* in_sizes, int n_in,
                              void* d_out, int out_size, void* d_ws, size_t ws_size,
                              hipStream_t stream) {
    const float* x   = (const float*)d_in[0];
    const int*   ei  = (const int*)d_in[1];
    const float* Wl0 = (const float*)d_in[2];
    const float* Wr0 = (const float*)d_in[3];
    const float* b0  = (const float*)d_in[4];
    const float* Wl1 = (const float*)d_in[5];
    const float* Wr1 = (const float*)d_in[6];
    const float* b1  = (const float*)d_in[7];
    const float* Wl2 = (const float*)d_in[8];
    const float* Wr2 = (const float*)d_in[9];
    const float* b2  = (const float*)d_in[10];

    const int N = in_sizes[0] / 256;   // 100000
    const int E = in_sizes[1] / 2;     // 1600000
    const int* src = ei;
    const int* dst = ei + E;

    char* p = (char*)d_ws;
    auto alloc = [&](size_t bytes) -> void* {
        void* r = (void*)p;
        p += (bytes + 255) & ~(size_t)255;
        return r;
    };
    int*      rowptr   = (int*)alloc((size_t)(N + 1) * 4);
    int*      chunkSum = (int*)alloc(64 * 4);
    int*      chunkOff = (int*)alloc(64 * 4);
    int*      bcnt     = (int*)alloc(MAXB * 4);
    int*      bbase    = (int*)alloc((MAXB + 1) * 4);
    int*      gcur     = (int*)alloc(MAXB * 4);
    int*      ssrc     = (int*)alloc((size_t)E * 4);
    _Float16* xl       = (_Float16*)alloc((size_t)N * 128 * 2);
    _Float16* xr       = (_Float16*)alloc((size_t)N * 128 * 2);
    _Float16* h0       = (_Float16*)alloc((size_t)N * 128 * 2);
    _Float16* gb       = (_Float16*)alloc((size_t)N * 128 * 2);
    _Float16* Wt0      = (_Float16*)alloc((size_t)256 * 256 * 2);
    _Float16* Wt1      = (_Float16*)alloc((size_t)256 * 128 * 2);
    _Float16* Wt2      = (_Float16*)alloc((size_t)128 * 128 * 2);

    unsigned* ebuf = (unsigned*)gb;

    float* out = (float*)d_out;
    float* x_final = out;                      // N*64
    float* out1    = out + (size_t)N * 64;     // N*128
    float* g       = out + (size_t)N * 192;    // N*128

    const int nb = (N + 255) >> 8;
    const int nbk = (E + BIN_CHUNK - 1) / BIN_CHUNK;

    // ---- CSR build (binned) ----
    hipMemsetAsync(bcnt, 0, MAXB * 4, stream);
    k_bhist<<<nbk, 256, 0, stream>>>(dst, bcnt, E);
    k_bscan<<<1, 64, 0, stream>>>(bcnt, bbase, gcur, nb);
    k_bin<<<nbk, 256, 0, stream>>>(src, dst, gcur, ebuf, E);
    k_nhist<<<nb, 256, 0, stream>>>(ebuf, bbase, rowptr, N);
    int nch = (N + 2047) / 2048;
    k_scan1<<<nch, 256, 0, stream>>>(rowptr, chunkSum, N);
    k_scan2<<<1, 64, 0, stream>>>(chunkSum, chunkOff, nch, rowptr + N);
    k_scan3<<<(N + 255) / 256, 256, 0, stream>>>(rowptr, chunkOff, N);
    k_bfill<<<nb, 256, 0, stream>>>(ebuf, bbase, rowptr, ssrc, N);

    // ---- weight prep ----
    k_wprep<256, 256><<<(256 * 256 + 255) / 256, 256, 0, stream>>>(Wl0, Wr0, Wt0);
    k_wprep<128, 256><<<(128 * 256 + 255) / 256, 256, 0, stream>>>(Wl1, Wr1, Wt1);
    k_wprep<128, 128><<<(128 * 128 + 255) / 256, 256, 0, stream>>>(Wl2, Wr2, Wt2);

    const int gGrid = (N + 63) / 64;

    // ---- layer 0 ----
    k_gemmM<256, 256, true><<<gGrid, 256, 0, stream>>>(x, Wt0, b0, xl, xr, N);
    k_agg<128, 0><<<(N + 31) / 32, 256, 0, stream>>>(xl, xr, rowptr, ssrc,
                                                     nullptr, nullptr, h0, N);

    // ---- layer 1 ----
    k_gemmM<128, 256, false><<<gGrid, 256, 0, stream>>>(h0, Wt1, b1, xl, xr, N);
    k_agg<128, 1><<<(N + 31) / 32, 256, 0, stream>>>(xl, xr, rowptr, ssrc,
                                                     out1, g, gb, N);

    // ---- layer 2 ----
    k_gemmM<128, 128, false><<<gGrid, 256, 0, stream>>>(gb, Wt2, b2, xl, xr, N);
    k_agg<64, 2><<<(N + 63) / 64, 256, 0, stream>>>(xl, xr, rowptr, ssrc,
                                                    x_final, nullptr, nullptr, N);
}

// Round 4
// 603.464 us; speedup vs baseline: 1.3243x; 1.3243x over previous
//
#include <hip/hip_runtime.h>
#include <stdint.h>

typedef __attribute__((ext_vector_type(4))) float f32x4;
typedef _Float16 half8 __attribute__((ext_vector_type(8)));
typedef _Float16 half4 __attribute__((ext_vector_type(4)));

// ---------------- CSR build via bucket binning ----------------

#define BIN_CHUNK 8192   // edges per block, 32/thread
#define MAXB 512         // >= nb = ceil(N/256)
#define DBINS 256        // degree-sort bins (deg clamped to 255)

__global__ __launch_bounds__(256) void k_bhist(const int* __restrict__ dst,
                                               int* __restrict__ bcnt, int E) {
    __shared__ int lh[MAXB];
    for (int i = threadIdx.x; i < MAXB; i += 256) lh[i] = 0;
    __syncthreads();
    const int base = blockIdx.x * BIN_CHUNK;
#pragma unroll 4
    for (int i = 0; i < BIN_CHUNK / 256; i++) {
        int e = base + i * 256 + threadIdx.x;
        if (e < E) atomicAdd(&lh[dst[e] >> 8], 1);
    }
    __syncthreads();
    for (int i = threadIdx.x; i < MAXB; i += 256)
        if (lh[i]) atomicAdd(&bcnt[i], lh[i]);
}

__global__ void k_bscan(const int* __restrict__ bcnt, int* __restrict__ bbase,
                        int* __restrict__ gcur, int nb) {
    if (threadIdx.x == 0 && blockIdx.x == 0) {
        int run = 0;
        for (int i = 0; i < nb; i++) { bbase[i] = run; gcur[i] = run; run += bcnt[i]; }
        bbase[nb] = run;
    }
}

__global__ __launch_bounds__(256) void k_bin(const int* __restrict__ src,
                                             const int* __restrict__ dst,
                                             int* __restrict__ gcur,
                                             unsigned* __restrict__ ebuf, int E) {
    __shared__ int lh[MAXB];
    __shared__ int lcur[MAXB];
    for (int i = threadIdx.x; i < MAXB; i += 256) lh[i] = 0;
    __syncthreads();
    const int base = blockIdx.x * BIN_CHUNK;
#pragma unroll 4
    for (int i = 0; i < BIN_CHUNK / 256; i++) {
        int e = base + i * 256 + threadIdx.x;
        if (e < E) atomicAdd(&lh[dst[e] >> 8], 1);
    }
    __syncthreads();
    for (int i = threadIdx.x; i < MAXB; i += 256)
        lcur[i] = lh[i] ? atomicAdd(&gcur[i], lh[i]) : 0;
    __syncthreads();
#pragma unroll 4
    for (int i = 0; i < BIN_CHUNK / 256; i++) {
        int e = base + i * 256 + threadIdx.x;
        if (e < E) {
            int d = dst[e];
            int pos = atomicAdd(&lcur[d >> 8], 1);
            ebuf[pos] = (unsigned)src[e] | ((unsigned)(d & 255) << 24);
        }
    }
}

__global__ __launch_bounds__(256) void k_nhist(const unsigned* __restrict__ ebuf,
                                               const int* __restrict__ bbase,
                                               int* __restrict__ deg, int N) {
    __shared__ int cnt[256];
    cnt[threadIdx.x] = 0;
    __syncthreads();
    const int b = blockIdx.x;
    const int lo = bbase[b], hi = bbase[b + 1];
    for (int e = lo + threadIdx.x; e < hi; e += 256)
        atomicAdd(&cnt[ebuf[e] >> 24], 1);
    __syncthreads();
    int n = (b << 8) + threadIdx.x;
    if (n < N) deg[n] = cnt[threadIdx.x];
}

__global__ __launch_bounds__(256) void k_bfill(const unsigned* __restrict__ ebuf,
                                               const int* __restrict__ bbase,
                                               const int* __restrict__ rowptr,
                                               int* __restrict__ ssrc, int N) {
    __shared__ int lc[256];
    const int b = blockIdx.x;
    int n = (b << 8) + threadIdx.x;
    lc[threadIdx.x] = (n < N) ? rowptr[n] : 0;
    __syncthreads();
    const int lo = bbase[b], hi = bbase[b + 1];
    for (int e = lo + threadIdx.x; e < hi; e += 256) {
        unsigned v = ebuf[e];
        int pos = atomicAdd(&lc[v >> 24], 1);
        ssrc[pos] = (int)(v & 0xFFFFFFu);
    }
}

// ---------------- rowptr scan ----------------

__global__ void k_scan1(int* __restrict__ buf, int* __restrict__ chunkSum, int N) {
    const int t = threadIdx.x;
    const int base = blockIdx.x * 2048 + t * 8;
    int v[8];
    int s = 0;
#pragma unroll
    for (int i = 0; i < 8; i++) {
        int idx = base + i;
        v[i] = (idx < N) ? buf[idx] : 0;
        s += v[i];
    }
    __shared__ int sh[256];
    sh[t] = s;
    __syncthreads();
    for (int off = 1; off < 256; off <<= 1) {
        int add = (t >= off) ? sh[t - off] : 0;
        __syncthreads();
        sh[t] += add;
        __syncthreads();
    }
    int excl = sh[t] - s;
    int run = excl;
#pragma unroll
    for (int i = 0; i < 8; i++) {
        int idx = base + i;
        if (idx < N) buf[idx] = run;
        run += v[i];
    }
    if (t == 255) chunkSum[blockIdx.x] = sh[255];
}

__global__ void k_scan2(const int* __restrict__ chunkSum, int* __restrict__ chunkOff,
                        int nch, int* __restrict__ rowptrN) {
    if (threadIdx.x == 0 && blockIdx.x == 0) {
        int run = 0;
        for (int i = 0; i < nch; i++) { chunkOff[i] = run; run += chunkSum[i]; }
        *rowptrN = run;
    }
}

__global__ void k_scan3(int* __restrict__ rowptr, const int* __restrict__ chunkOff, int N) {
    int i = blockIdx.x * 256 + threadIdx.x;
    if (i < N) rowptr[i] += chunkOff[i >> 11];
}

// ---------------- degree counting-sort (descending) ----------------
// perm = nodes sorted by degree descending; waves then process equal-degree
// nodes (no max-of-8 tail), heavy blocks launch first. Per-node edge order is
// unchanged -> bit-identical summation vs unsorted.

__global__ __launch_bounds__(256) void k_dhist(const int* __restrict__ rowptr,
                                               int* __restrict__ dcnt, int N) {
    __shared__ int lh[DBINS];
    lh[threadIdx.x] = 0;
    __syncthreads();
    int i = blockIdx.x * 256 + threadIdx.x;
    if (i < N) {
        int d = rowptr[i + 1] - rowptr[i];
        if (d > 255) d = 255;
        atomicAdd(&lh[d], 1);
    }
    __syncthreads();
    if (lh[threadIdx.x]) atomicAdd(&dcnt[threadIdx.x], lh[threadIdx.x]);
}

__global__ void k_dscan(const int* __restrict__ dcnt, int* __restrict__ dcur) {
    if (threadIdx.x == 0 && blockIdx.x == 0) {
        int run = 0;
        for (int d = DBINS - 1; d >= 0; d--) { dcur[d] = run; run += dcnt[d]; }
    }
}

__global__ __launch_bounds__(256) void k_dfill(const int* __restrict__ rowptr,
                                               int* __restrict__ dcur,
                                               int* __restrict__ perm, int N) {
    __shared__ int lh[DBINS];
    __shared__ int lbase[DBINS];
    lh[threadIdx.x] = 0;
    __syncthreads();
    int i = blockIdx.x * 256 + threadIdx.x;
    int d = 0, lpos = 0;
    bool valid = (i < N);
    if (valid) {
        d = rowptr[i + 1] - rowptr[i];
        if (d > 255) d = 255;
        lpos = atomicAdd(&lh[d], 1);
    }
    __syncthreads();
    lbase[threadIdx.x] = lh[threadIdx.x] ? atomicAdd(&dcur[threadIdx.x], lh[threadIdx.x]) : 0;
    __syncthreads();
    if (valid) perm[lbase[d] + lpos] = i;
}

// ---------------- weight prep: k-blocked layout ----------------

template <int K, int NCOLT>
__global__ void k_wprep(const float* __restrict__ Wl, const float* __restrict__ Wr,
                        _Float16* __restrict__ Wt) {
    constexpr int NCOL = NCOLT / 2;
    int i = blockIdx.x * 256 + threadIdx.x;
    if (i < K * NCOLT) {
        int n = i / K, k = i - n * K;
        float v = (n < NCOL) ? Wl[(size_t)k * NCOL + n] : Wr[(size_t)k * NCOL + (n - NCOL)];
        Wt[(size_t)(k >> 5) * (NCOLT * 32) + n * 32 + (k & 31)] = (_Float16)v;
    }
}

// ---------------- MFMA GEMM: [Cl|Cr] = A @ [Wl|Wr] ----------------

template <int K, int NCOLT, bool AF32>
__global__ __launch_bounds__(256) void k_gemmM(const void* __restrict__ Av,
                                               const _Float16* __restrict__ Wt,
                                               const float* __restrict__ bias,
                                               _Float16* __restrict__ Cl,
                                               _Float16* __restrict__ Cr, int M) {
    constexpr int NCOL = NCOLT / 2;
    constexpr int WC = NCOLT / 4;
    constexpr int NT = WC / 16;
    constexpr int AS = K + 8;
    constexpr int CS = NCOLT + 8;
    constexpr int MAXS = (K > NCOLT ? K : NCOLT) + 8;
    __shared__ _Float16 sh[64 * MAXS];

    const int tid = threadIdx.x;
    const int lane = tid & 63;
    const int wave = tid >> 6;
    const int quad = lane >> 4;
    const int l16 = lane & 15;
    const int m0 = blockIdx.x * 64;
    const int colbase = wave * WC;

    if (AF32) {
        const float* A = (const float*)Av;
#pragma unroll
        for (int i = 0; i < K / 16; i++) {
            int off = i * 1024 + tid * 4;
            int row = off / K, col = off % K;
            f32x4 u = {0.f, 0.f, 0.f, 0.f};
            if (m0 + row < M) u = *(const f32x4*)(A + (size_t)(m0 + row) * K + col);
            half4 h = {(_Float16)u[0], (_Float16)u[1], (_Float16)u[2], (_Float16)u[3]};
            *(half4*)(sh + row * AS + col) = h;
        }
    } else {
        const _Float16* A = (const _Float16*)Av;
#pragma unroll
        for (int i = 0; i < K / 32; i++) {
            int off = i * 2048 + tid * 8;
            int row = off / K, col = off % K;
            half8 u = {0, 0, 0, 0, 0, 0, 0, 0};
            if (m0 + row < M) u = *(const half8*)(A + (size_t)(m0 + row) * K + col);
            *(half8*)(sh + row * AS + col) = u;
        }
    }
    __syncthreads();

    f32x4 acc[4][NT];
#pragma unroll
    for (int rg = 0; rg < 4; rg++)
#pragma unroll
        for (int t = 0; t < NT; t++) acc[rg][t] = (f32x4){0.f, 0.f, 0.f, 0.f};

#pragma unroll
    for (int k0 = 0; k0 < K; k0 += 32) {
        half8 a[4];
#pragma unroll
        for (int rg = 0; rg < 4; rg++)
            a[rg] = *(const half8*)(sh + (rg * 16 + l16) * AS + k0 + quad * 8);
        half8 b[NT];
        const _Float16* Wk = Wt + (size_t)(k0 >> 5) * (NCOLT * 32);
#pragma unroll
        for (int t = 0; t < NT; t++)
            b[t] = *(const half8*)(Wk + (colbase + t * 16 + l16) * 32 + quad * 8);
#pragma unroll
        for (int rg = 0; rg < 4; rg++)
#pragma unroll
            for (int t = 0; t < NT; t++)
                acc[rg][t] = __builtin_amdgcn_mfma_f32_16x16x32_f16(b[t], a[rg], acc[rg][t], 0, 0, 0);
    }

    __syncthreads();

#pragma unroll
    for (int t = 0; t < NT; t++) {
        int c0 = colbase + t * 16 + quad * 4;
        f32x4 bv = {0.f, 0.f, 0.f, 0.f};
        if (c0 >= NCOL) bv = *(const f32x4*)(bias + (c0 - NCOL));
#pragma unroll
        for (int rg = 0; rg < 4; rg++) {
            half4 h = {(_Float16)(acc[rg][t][0] + bv[0]), (_Float16)(acc[rg][t][1] + bv[1]),
                       (_Float16)(acc[rg][t][2] + bv[2]), (_Float16)(acc[rg][t][3] + bv[3])};
            *(half4*)(sh + (rg * 16 + l16) * CS + c0) = h;
        }
    }
    __syncthreads();

#pragma unroll
    for (int i = 0; i < (64 * NCOL) / 2048; i++) {
        int off = i * 2048 + tid * 8;
        int row = off / NCOL, col = off % NCOL;
        if (m0 + row < M) {
            *(half8*)(Cl + (size_t)(m0 + row) * NCOL + col) = *(const half8*)(sh + row * CS + col);
            *(half8*)(Cr + (size_t)(m0 + row) * NCOL + col) = *(const half8*)(sh + row * CS + NCOL + col);
        }
    }
}

// ---------------- aggregation (round-2 structure + degree-sorted perm) ----------------
// Thread-group owns one node (16 ch/lane), serial edge walk with 4-edge unroll
// (8 b128 gathers in flight). Node identity comes from perm[] (degree-descending)
// so a wave's 8 nodes have ~equal degree -> no max-of-8 trip-count tail.

template <int COUT, int MODE>
__global__ __launch_bounds__(256) void k_agg(const half8* __restrict__ xl,
                                             const half8* __restrict__ xr,
                                             const int* __restrict__ rowptr,
                                             const int* __restrict__ ssrc,
                                             const int* __restrict__ perm,
                                             float* __restrict__ outF1,
                                             float* __restrict__ outF2,
                                             _Float16* __restrict__ outH, int N) {
    constexpr int LPN = COUT / 16;
    constexpr int NPB = 256 / LPN;
    constexpr int C8 = COUT / 8;
    const int tid = threadIdx.x;
    const int c = tid % LPN;
    const int idx = blockIdx.x * NPB + tid / LPN;
    if (idx >= N) return;
    const int n = perm[idx];

    const int rp0 = rowptr[n];
    const int rp1 = rowptr[n + 1];
    float acc[16];
#pragma unroll
    for (int i = 0; i < 16; i++) acc[i] = 0.f;

    const size_t cb = (size_t)c * 2;
    int e = rp0;
    for (; e + 3 < rp1; e += 4) {
        int s0 = ssrc[e], s1 = ssrc[e + 1], s2 = ssrc[e + 2], s3 = ssrc[e + 3];
        half8 v0a = xl[(size_t)s0 * C8 + cb], v0b = xl[(size_t)s0 * C8 + cb + 1];
        half8 v1a = xl[(size_t)s1 * C8 + cb], v1b = xl[(size_t)s1 * C8 + cb + 1];
        half8 v2a = xl[(size_t)s2 * C8 + cb], v2b = xl[(size_t)s2 * C8 + cb + 1];
        half8 v3a = xl[(size_t)s3 * C8 + cb], v3b = xl[(size_t)s3 * C8 + cb + 1];
#pragma unroll
        for (int i = 0; i < 8; i++) {
            acc[i] += (float)v0a[i] + (float)v1a[i] + (float)v2a[i] + (float)v3a[i];
            acc[8 + i] += (float)v0b[i] + (float)v1b[i] + (float)v2b[i] + (float)v3b[i];
        }
    }
    for (; e < rp1; e++) {
        int s = ssrc[e];
        half8 va = xl[(size_t)s * C8 + cb], vb = xl[(size_t)s * C8 + cb + 1];
#pragma unroll
        for (int i = 0; i < 8; i++) {
            acc[i] += (float)va[i];
            acc[8 + i] += (float)vb[i];
        }
    }

    const int deg = rp1 - rp0;
    const float scale = 1.0f / (float)(deg > 1 ? deg : 1);
    half8 x0 = xr[(size_t)n * C8 + cb];
    half8 x1 = xr[(size_t)n * C8 + cb + 1];
    float res[16];
#pragma unroll
    for (int i = 0; i < 8; i++) {
        res[i] = acc[i] * scale + (float)x0[i];
        res[8 + i] = acc[8 + i] * scale + (float)x1[i];
    }

    const size_t ob = (size_t)n * COUT + (size_t)c * 16;
    if (MODE == 0) {
        half8 h0v, h1v;
#pragma unroll
        for (int i = 0; i < 8; i++) {
            h0v[i] = (_Float16)(res[i] > 0.f ? res[i] : 0.f);
            h1v[i] = (_Float16)(res[8 + i] > 0.f ? res[8 + i] : 0.f);
        }
        *(half8*)(outH + ob) = h0v;
        *(half8*)(outH + ob + 8) = h1v;
    } else if (MODE == 1) {
#pragma unroll
        for (int q = 0; q < 4; q++) {
            f32x4 v = {res[q * 4], res[q * 4 + 1], res[q * 4 + 2], res[q * 4 + 3]};
            *(f32x4*)(outF1 + ob + q * 4) = v;
            f32x4 z = {v[0] > 0.f ? v[0] : 0.f, v[1] > 0.f ? v[1] : 0.f,
                       v[2] > 0.f ? v[2] : 0.f, v[3] > 0.f ? v[3] : 0.f};
            *(f32x4*)(outF2 + ob + q * 4) = z;
        }
        half8 h0v, h1v;
#pragma unroll
        for (int i = 0; i < 8; i++) {
            h0v[i] = (_Float16)(res[i] > 0.f ? res[i] : 0.f);
            h1v[i] = (_Float16)(res[8 + i] > 0.f ? res[8 + i] : 0.f);
        }
        *(half8*)(outH + ob) = h0v;
        *(half8*)(outH + ob + 8) = h1v;
    } else {
#pragma unroll
        for (int q = 0; q < 4; q++) {
            f32x4 v = {res[q * 4], res[q * 4 + 1], res[q * 4 + 2], res[q * 4 + 3]};
            *(f32x4*)(outF1 + ob + q * 4) = v;
        }
    }
}

// ---------------- launch ----------------

extern "C" void kernel_launch(void* const* d_in, const int* in_sizes, int n_in,
                              void* d_out, int out_size, void* d_ws, size_t ws_size,
                              hipStream_t stream) {
    const float* x   = (const float*)d_in[0];
    const int*   ei  = (const int*)d_in[1];
    const float* Wl0 = (const float*)d_in[2];
    const float* Wr0 = (const float*)d_in[3];
    const float* b0  = (const float*)d_in[4];
    const float* Wl1 = (const float*)d_in[5];
    const float* Wr1 = (const float*)d_in[6];
    const float* b1  = (const float*)d_in[7];
    const float* Wl2 = (const float*)d_in[8];
    const float* Wr2 = (const float*)d_in[9];
    const float* b2  = (const float*)d_in[10];

    const int N = in_sizes[0] / 256;   // 100000
    const int E = in_sizes[1] / 2;     // 1600000
    const int* src = ei;
    const int* dst = ei + E;

    char* p = (char*)d_ws;
    auto alloc = [&](size_t bytes) -> void* {
        void* r = (void*)p;
        p += (bytes + 255) & ~(size_t)255;
        return r;
    };
    int*      rowptr   = (int*)alloc((size_t)(N + 1) * 4);
    int*      chunkSum = (int*)alloc(64 * 4);
    int*      chunkOff = (int*)alloc(64 * 4);
    int*      bcnt     = (int*)alloc(MAXB * 4);
    int*      bbase    = (int*)alloc((MAXB + 1) * 4);
    int*      gcur     = (int*)alloc(MAXB * 4);
    int*      dcnt     = (int*)alloc(DBINS * 4);
    int*      dcur     = (int*)alloc(DBINS * 4);
    int*      perm     = (int*)alloc((size_t)N * 4);
    int*      ssrc     = (int*)alloc((size_t)E * 4);
    _Float16* xl       = (_Float16*)alloc((size_t)N * 128 * 2);
    _Float16* xr       = (_Float16*)alloc((size_t)N * 128 * 2);
    _Float16* h0       = (_Float16*)alloc((size_t)N * 128 * 2);
    _Float16* gb       = (_Float16*)alloc((size_t)N * 128 * 2);
    _Float16* Wt0      = (_Float16*)alloc((size_t)256 * 256 * 2);
    _Float16* Wt1      = (_Float16*)alloc((size_t)256 * 128 * 2);
    _Float16* Wt2      = (_Float16*)alloc((size_t)128 * 128 * 2);

    // ebuf (binned packed edges, E*4 bytes) aliases gb: dead before gb's first
    // write (layer-1 agg), stream-ordered so no hazard.
    unsigned* ebuf = (unsigned*)gb;

    float* out = (float*)d_out;
    float* x_final = out;                      // N*64
    float* out1    = out + (size_t)N * 64;     // N*128
    float* g       = out + (size_t)N * 192;    // N*128

    const int nb = (N + 255) >> 8;
    const int nbk = (E + BIN_CHUNK - 1) / BIN_CHUNK;
    const int nnb = (N + 255) / 256;

    // ---- CSR build (binned) ----
    hipMemsetAsync(bcnt, 0, MAXB * 4, stream);
    hipMemsetAsync(dcnt, 0, DBINS * 4, stream);
    k_bhist<<<nbk, 256, 0, stream>>>(dst, bcnt, E);
    k_bscan<<<1, 64, 0, stream>>>(bcnt, bbase, gcur, nb);
    k_bin<<<nbk, 256, 0, stream>>>(src, dst, gcur, ebuf, E);
    k_nhist<<<nb, 256, 0, stream>>>(ebuf, bbase, rowptr, N);
    int nch = (N + 2047) / 2048;
    k_scan1<<<nch, 256, 0, stream>>>(rowptr, chunkSum, N);
    k_scan2<<<1, 64, 0, stream>>>(chunkSum, chunkOff, nch, rowptr + N);
    k_scan3<<<(N + 255) / 256, 256, 0, stream>>>(rowptr, chunkOff, N);
    k_bfill<<<nb, 256, 0, stream>>>(ebuf, bbase, rowptr, ssrc, N);

    // ---- degree sort (descending) ----
    k_dhist<<<nnb, 256, 0, stream>>>(rowptr, dcnt, N);
    k_dscan<<<1, 64, 0, stream>>>(dcnt, dcur);
    k_dfill<<<nnb, 256, 0, stream>>>(rowptr, dcur, perm, N);

    // ---- weight prep ----
    k_wprep<256, 256><<<(256 * 256 + 255) / 256, 256, 0, stream>>>(Wl0, Wr0, Wt0);
    k_wprep<128, 256><<<(128 * 256 + 255) / 256, 256, 0, stream>>>(Wl1, Wr1, Wt1);
    k_wprep<128, 128><<<(128 * 128 + 255) / 256, 256, 0, stream>>>(Wl2, Wr2, Wt2);

    const int gGrid = (N + 63) / 64;

    // ---- layer 0 ----
    k_gemmM<256, 256, true><<<gGrid, 256, 0, stream>>>(x, Wt0, b0, xl, xr, N);
    k_agg<128, 0><<<(N + 31) / 32, 256, 0, stream>>>((const half8*)xl, (const half8*)xr,
                                                     rowptr, ssrc, perm,
                                                     nullptr, nullptr, h0, N);

    // ---- layer 1 ----
    k_gemmM<128, 256, false><<<gGrid, 256, 0, stream>>>(h0, Wt1, b1, xl, xr, N);
    k_agg<128, 1><<<(N + 31) / 32, 256, 0, stream>>>((const half8*)xl, (const half8*)xr,
                                                     rowptr, ssrc, perm,
                                                     out1, g, gb, N);

    // ---- layer 2 ----
    k_gemmM<128, 128, false><<<gGrid, 256, 0, stream>>>(gb, Wt2, b2, xl, xr, N);
    k_agg<64, 2><<<(N + 63) / 64, 256, 0, stream>>>((const half8*)xl, (const half8*)xr,
                                                    rowptr, ssrc, perm,
                                                    x_final, nullptr, nullptr, N);
}

// Round 5
// 553.242 us; speedup vs baseline: 1.4445x; 1.0908x over previous
//
#include <hip/hip_runtime.h>
#include <stdint.h>

typedef __attribute__((ext_vector_type(4))) float f32x4;
typedef _Float16 half8 __attribute__((ext_vector_type(8)));
typedef _Float16 half4 __attribute__((ext_vector_type(4)));

// ---------------- CSR build via bucket binning ----------------

#define BIN_CHUNK 8192   // edges per block, 32/thread
#define MAXB 512         // >= nb = ceil(N/256)

__global__ __launch_bounds__(256) void k_bhist(const int* __restrict__ dst,
                                               int* __restrict__ bcnt, int E) {
    __shared__ int lh[MAXB];
    for (int i = threadIdx.x; i < MAXB; i += 256) lh[i] = 0;
    __syncthreads();
    const int base = blockIdx.x * BIN_CHUNK;
#pragma unroll 4
    for (int i = 0; i < BIN_CHUNK / 256; i++) {
        int e = base + i * 256 + threadIdx.x;
        if (e < E) atomicAdd(&lh[dst[e] >> 8], 1);
    }
    __syncthreads();
    for (int i = threadIdx.x; i < MAXB; i += 256)
        if (lh[i]) atomicAdd(&bcnt[i], lh[i]);
}

// Parallel exclusive scan over n<=2048 ints, single block of 512 threads.
// Replaces the serial one-thread scans (dependent L2-latency chain ~40us).
// out0 = exclusive prefix; out1 (optional) = copy; tot (optional) = total sum.
__global__ __launch_bounds__(512) void k_pscan(const int* __restrict__ in,
                                               int* __restrict__ out0,
                                               int* __restrict__ out1,
                                               int* __restrict__ tot, int n) {
    __shared__ int sh[512];
    const int t = threadIdx.x;
    int v[4];
    int s = 0;
#pragma unroll
    for (int i = 0; i < 4; i++) {
        int idx = t * 4 + i;
        v[i] = (idx < n) ? in[idx] : 0;
        s += v[i];
    }
    sh[t] = s;
    __syncthreads();
    for (int off = 1; off < 512; off <<= 1) {
        int add = (t >= off) ? sh[t - off] : 0;
        __syncthreads();
        sh[t] += add;
        __syncthreads();
    }
    int excl = sh[t] - s;
#pragma unroll
    for (int i = 0; i < 4; i++) {
        int idx = t * 4 + i;
        if (idx < n) {
            out0[idx] = excl;
            if (out1) out1[idx] = excl;
        }
        excl += v[i];
    }
    if (t == 511 && tot) *tot = sh[511];
}

__global__ __launch_bounds__(256) void k_bin(const int* __restrict__ src,
                                             const int* __restrict__ dst,
                                             int* __restrict__ gcur,
                                             unsigned* __restrict__ ebuf, int E) {
    __shared__ int lh[MAXB];
    __shared__ int lcur[MAXB];
    for (int i = threadIdx.x; i < MAXB; i += 256) lh[i] = 0;
    __syncthreads();
    const int base = blockIdx.x * BIN_CHUNK;
#pragma unroll 4
    for (int i = 0; i < BIN_CHUNK / 256; i++) {
        int e = base + i * 256 + threadIdx.x;
        if (e < E) atomicAdd(&lh[dst[e] >> 8], 1);
    }
    __syncthreads();
    for (int i = threadIdx.x; i < MAXB; i += 256)
        lcur[i] = lh[i] ? atomicAdd(&gcur[i], lh[i]) : 0;
    __syncthreads();
#pragma unroll 4
    for (int i = 0; i < BIN_CHUNK / 256; i++) {
        int e = base + i * 256 + threadIdx.x;
        if (e < E) {
            int d = dst[e];
            int pos = atomicAdd(&lcur[d >> 8], 1);
            ebuf[pos] = (unsigned)src[e] | ((unsigned)(d & 255) << 24);
        }
    }
}

__global__ __launch_bounds__(256) void k_nhist(const unsigned* __restrict__ ebuf,
                                               const int* __restrict__ bbase,
                                               int* __restrict__ deg, int N) {
    __shared__ int cnt[256];
    cnt[threadIdx.x] = 0;
    __syncthreads();
    const int b = blockIdx.x;
    const int lo = bbase[b], hi = bbase[b + 1];
    for (int e = lo + threadIdx.x; e < hi; e += 256)
        atomicAdd(&cnt[ebuf[e] >> 24], 1);
    __syncthreads();
    int n = (b << 8) + threadIdx.x;
    if (n < N) deg[n] = cnt[threadIdx.x];
}

__global__ __launch_bounds__(256) void k_bfill(const unsigned* __restrict__ ebuf,
                                               const int* __restrict__ bbase,
                                               const int* __restrict__ rowptr,
                                               int* __restrict__ ssrc, int N) {
    __shared__ int lc[256];
    const int b = blockIdx.x;
    int n = (b << 8) + threadIdx.x;
    lc[threadIdx.x] = (n < N) ? rowptr[n] : 0;
    __syncthreads();
    const int lo = bbase[b], hi = bbase[b + 1];
    for (int e = lo + threadIdx.x; e < hi; e += 256) {
        unsigned v = ebuf[e];
        int pos = atomicAdd(&lc[v >> 24], 1);
        ssrc[pos] = (int)(v & 0xFFFFFFu);
    }
}

// ---------------- rowptr scan (block-level) ----------------

__global__ void k_scan1(int* __restrict__ buf, int* __restrict__ chunkSum, int N) {
    const int t = threadIdx.x;
    const int base = blockIdx.x * 2048 + t * 8;
    int v[8];
    int s = 0;
#pragma unroll
    for (int i = 0; i < 8; i++) {
        int idx = base + i;
        v[i] = (idx < N) ? buf[idx] : 0;
        s += v[i];
    }
    __shared__ int sh[256];
    sh[t] = s;
    __syncthreads();
    for (int off = 1; off < 256; off <<= 1) {
        int add = (t >= off) ? sh[t - off] : 0;
        __syncthreads();
        sh[t] += add;
        __syncthreads();
    }
    int excl = sh[t] - s;
    int run = excl;
#pragma unroll
    for (int i = 0; i < 8; i++) {
        int idx = base + i;
        if (idx < N) buf[idx] = run;
        run += v[i];
    }
    if (t == 255) chunkSum[blockIdx.x] = sh[255];
}

__global__ void k_scan3(int* __restrict__ rowptr, const int* __restrict__ chunkOff, int N) {
    int i = blockIdx.x * 256 + threadIdx.x;
    if (i < N) rowptr[i] += chunkOff[i >> 11];
}

// ---------------- weight prep (all three layers, one launch) ----------------
// Wt[(k>>5)*(NCOLT*32) + n*32 + (k&31)] = f16( n<NCOL ? Wl[k][n] : Wr[k][n-NCOL] )

template <int K, int NCOLT>
__device__ inline void wprep_one(const float* __restrict__ Wl, const float* __restrict__ Wr,
                                 _Float16* __restrict__ Wt, int i) {
    constexpr int NCOL = NCOLT / 2;
    int n = i / K, k = i - n * K;
    float v = (n < NCOL) ? Wl[(size_t)k * NCOL + n] : Wr[(size_t)k * NCOL + (n - NCOL)];
    Wt[(size_t)(k >> 5) * (NCOLT * 32) + n * 32 + (k & 31)] = (_Float16)v;
}

__global__ __launch_bounds__(256) void k_wprepAll(
    const float* __restrict__ Wl0, const float* __restrict__ Wr0,
    const float* __restrict__ Wl1, const float* __restrict__ Wr1,
    const float* __restrict__ Wl2, const float* __restrict__ Wr2,
    _Float16* __restrict__ Wt0, _Float16* __restrict__ Wt1, _Float16* __restrict__ Wt2) {
    int i = blockIdx.x * 256 + threadIdx.x;
    if (i < 65536) wprep_one<256, 256>(Wl0, Wr0, Wt0, i);
    else if (i < 98304) wprep_one<128, 256>(Wl1, Wr1, Wt1, i - 65536);
    else if (i < 114688) wprep_one<128, 128>(Wl2, Wr2, Wt2, i - 98304);
}

// ---------------- MFMA GEMM: [Cl|Cr] = A @ [Wl|Wr] ----------------

template <int K, int NCOLT, bool AF32>
__global__ __launch_bounds__(256) void k_gemmM(const void* __restrict__ Av,
                                               const _Float16* __restrict__ Wt,
                                               const float* __restrict__ bias,
                                               _Float16* __restrict__ Cl,
                                               _Float16* __restrict__ Cr, int M) {
    constexpr int NCOL = NCOLT / 2;
    constexpr int WC = NCOLT / 4;
    constexpr int NT = WC / 16;
    constexpr int AS = K + 8;
    constexpr int CS = NCOLT + 8;
    constexpr int MAXS = (K > NCOLT ? K : NCOLT) + 8;
    __shared__ _Float16 sh[64 * MAXS];

    const int tid = threadIdx.x;
    const int lane = tid & 63;
    const int wave = tid >> 6;
    const int quad = lane >> 4;
    const int l16 = lane & 15;
    const int m0 = blockIdx.x * 64;
    const int colbase = wave * WC;

    if (AF32) {
        const float* A = (const float*)Av;
#pragma unroll
        for (int i = 0; i < K / 16; i++) {
            int off = i * 1024 + tid * 4;
            int row = off / K, col = off % K;
            f32x4 u = {0.f, 0.f, 0.f, 0.f};
            if (m0 + row < M) u = *(const f32x4*)(A + (size_t)(m0 + row) * K + col);
            half4 h = {(_Float16)u[0], (_Float16)u[1], (_Float16)u[2], (_Float16)u[3]};
            *(half4*)(sh + row * AS + col) = h;
        }
    } else {
        const _Float16* A = (const _Float16*)Av;
#pragma unroll
        for (int i = 0; i < K / 32; i++) {
            int off = i * 2048 + tid * 8;
            int row = off / K, col = off % K;
            half8 u = {0, 0, 0, 0, 0, 0, 0, 0};
            if (m0 + row < M) u = *(const half8*)(A + (size_t)(m0 + row) * K + col);
            *(half8*)(sh + row * AS + col) = u;
        }
    }
    __syncthreads();

    f32x4 acc[4][NT];
#pragma unroll
    for (int rg = 0; rg < 4; rg++)
#pragma unroll
        for (int t = 0; t < NT; t++) acc[rg][t] = (f32x4){0.f, 0.f, 0.f, 0.f};

#pragma unroll
    for (int k0 = 0; k0 < K; k0 += 32) {
        half8 a[4];
#pragma unroll
        for (int rg = 0; rg < 4; rg++)
            a[rg] = *(const half8*)(sh + (rg * 16 + l16) * AS + k0 + quad * 8);
        half8 b[NT];
        const _Float16* Wk = Wt + (size_t)(k0 >> 5) * (NCOLT * 32);
#pragma unroll
        for (int t = 0; t < NT; t++)
            b[t] = *(const half8*)(Wk + (colbase + t * 16 + l16) * 32 + quad * 8);
#pragma unroll
        for (int rg = 0; rg < 4; rg++)
#pragma unroll
            for (int t = 0; t < NT; t++)
                acc[rg][t] = __builtin_amdgcn_mfma_f32_16x16x32_f16(b[t], a[rg], acc[rg][t], 0, 0, 0);
    }

    __syncthreads();

#pragma unroll
    for (int t = 0; t < NT; t++) {
        int c0 = colbase + t * 16 + quad * 4;
        f32x4 bv = {0.f, 0.f, 0.f, 0.f};
        if (c0 >= NCOL) bv = *(const f32x4*)(bias + (c0 - NCOL));
#pragma unroll
        for (int rg = 0; rg < 4; rg++) {
            half4 h = {(_Float16)(acc[rg][t][0] + bv[0]), (_Float16)(acc[rg][t][1] + bv[1]),
                       (_Float16)(acc[rg][t][2] + bv[2]), (_Float16)(acc[rg][t][3] + bv[3])};
            *(half4*)(sh + (rg * 16 + l16) * CS + c0) = h;
        }
    }
    __syncthreads();

#pragma unroll
    for (int i = 0; i < (64 * NCOL) / 2048; i++) {
        int off = i * 2048 + tid * 8;
        int row = off / NCOL, col = off % NCOL;
        if (m0 + row < M) {
            *(half8*)(Cl + (size_t)(m0 + row) * NCOL + col) = *(const half8*)(sh + row * CS + col);
            *(half8*)(Cr + (size_t)(m0 + row) * NCOL + col) = *(const half8*)(sh + row * CS + NCOL + col);
        }
    }
}

// ---------------- aggregation (round-2 proven structure) ----------------
// Thread-group owns one node (16 ch/lane), serial edge walk with 4-edge unroll
// (8 b128 gathers in flight). Measured: FETCH at the unique-line floor, rate
// ~3.8 TB/s = random-gather service ceiling (balance fixes in R3/R4 both failed).

template <int COUT, int MODE>
__global__ __launch_bounds__(256) void k_agg(const half8* __restrict__ xl,
                                             const half8* __restrict__ xr,
                                             const int* __restrict__ rowptr,
                                             const int* __restrict__ ssrc,
                                             float* __restrict__ outF1,
                                             float* __restrict__ outF2,
                                             _Float16* __restrict__ outH, int N) {
    constexpr int LPN = COUT / 16;
    constexpr int NPB = 256 / LPN;
    constexpr int C8 = COUT / 8;
    const int tid = threadIdx.x;
    const int c = tid % LPN;
    const int n = blockIdx.x * NPB + tid / LPN;
    if (n >= N) return;

    const int rp0 = rowptr[n];
    const int rp1 = rowptr[n + 1];
    float acc[16];
#pragma unroll
    for (int i = 0; i < 16; i++) acc[i] = 0.f;

    const size_t cb = (size_t)c * 2;
    int e = rp0;
    for (; e + 3 < rp1; e += 4) {
        int s0 = ssrc[e], s1 = ssrc[e + 1], s2 = ssrc[e + 2], s3 = ssrc[e + 3];
        half8 v0a = xl[(size_t)s0 * C8 + cb], v0b = xl[(size_t)s0 * C8 + cb + 1];
        half8 v1a = xl[(size_t)s1 * C8 + cb], v1b = xl[(size_t)s1 * C8 + cb + 1];
        half8 v2a = xl[(size_t)s2 * C8 + cb], v2b = xl[(size_t)s2 * C8 + cb + 1];
        half8 v3a = xl[(size_t)s3 * C8 + cb], v3b = xl[(size_t)s3 * C8 + cb + 1];
#pragma unroll
        for (int i = 0; i < 8; i++) {
            acc[i] += (float)v0a[i] + (float)v1a[i] + (float)v2a[i] + (float)v3a[i];
            acc[8 + i] += (float)v0b[i] + (float)v1b[i] + (float)v2b[i] + (float)v3b[i];
        }
    }
    for (; e < rp1; e++) {
        int s = ssrc[e];
        half8 va = xl[(size_t)s * C8 + cb], vb = xl[(size_t)s * C8 + cb + 1];
#pragma unroll
        for (int i = 0; i < 8; i++) {
            acc[i] += (float)va[i];
            acc[8 + i] += (float)vb[i];
        }
    }

    const int deg = rp1 - rp0;
    const float scale = 1.0f / (float)(deg > 1 ? deg : 1);
    half8 x0 = xr[(size_t)n * C8 + cb];
    half8 x1 = xr[(size_t)n * C8 + cb + 1];
    float res[16];
#pragma unroll
    for (int i = 0; i < 8; i++) {
        res[i] = acc[i] * scale + (float)x0[i];
        res[8 + i] = acc[8 + i] * scale + (float)x1[i];
    }

    const size_t ob = (size_t)n * COUT + (size_t)c * 16;
    if (MODE == 0) {
        half8 h0v, h1v;
#pragma unroll
        for (int i = 0; i < 8; i++) {
            h0v[i] = (_Float16)(res[i] > 0.f ? res[i] : 0.f);
            h1v[i] = (_Float16)(res[8 + i] > 0.f ? res[8 + i] : 0.f);
        }
        *(half8*)(outH + ob) = h0v;
        *(half8*)(outH + ob + 8) = h1v;
    } else if (MODE == 1) {
#pragma unroll
        for (int q = 0; q < 4; q++) {
            f32x4 v = {res[q * 4], res[q * 4 + 1], res[q * 4 + 2], res[q * 4 + 3]};
            *(f32x4*)(outF1 + ob + q * 4) = v;
            f32x4 z = {v[0] > 0.f ? v[0] : 0.f, v[1] > 0.f ? v[1] : 0.f,
                       v[2] > 0.f ? v[2] : 0.f, v[3] > 0.f ? v[3] : 0.f};
            *(f32x4*)(outF2 + ob + q * 4) = z;
        }
        half8 h0v, h1v;
#pragma unroll
        for (int i = 0; i < 8; i++) {
            h0v[i] = (_Float16)(res[i] > 0.f ? res[i] : 0.f);
            h1v[i] = (_Float16)(res[8 + i] > 0.f ? res[8 + i] : 0.f);
        }
        *(half8*)(outH + ob) = h0v;
        *(half8*)(outH + ob + 8) = h1v;
    } else {
#pragma unroll
        for (int q = 0; q < 4; q++) {
            f32x4 v = {res[q * 4], res[q * 4 + 1], res[q * 4 + 2], res[q * 4 + 3]};
            *(f32x4*)(outF1 + ob + q * 4) = v;
        }
    }
}

// ---------------- launch ----------------

extern "C" void kernel_launch(void* const* d_in, const int* in_sizes, int n_in,
                              void* d_out, int out_size, void* d_ws, size_t ws_size,
                              hipStream_t stream) {
    const float* x   = (const float*)d_in[0];
    const int*   ei  = (const int*)d_in[1];
    const float* Wl0 = (const float*)d_in[2];
    const float* Wr0 = (const float*)d_in[3];
    const float* b0  = (const float*)d_in[4];
    const float* Wl1 = (const float*)d_in[5];
    const float* Wr1 = (const float*)d_in[6];
    const float* b1  = (const float*)d_in[7];
    const float* Wl2 = (const float*)d_in[8];
    const float* Wr2 = (const float*)d_in[9];
    const float* b2  = (const float*)d_in[10];

    const int N = in_sizes[0] / 256;   // 100000
    const int E = in_sizes[1] / 2;     // 1600000
    const int* src = ei;
    const int* dst = ei + E;

    char* p = (char*)d_ws;
    auto alloc = [&](size_t bytes) -> void* {
        void* r = (void*)p;
        p += (bytes + 255) & ~(size_t)255;
        return r;
    };
    int*      rowptr   = (int*)alloc((size_t)(N + 1) * 4);
    int*      chunkSum = (int*)alloc(64 * 4);
    int*      chunkOff = (int*)alloc(64 * 4);
    int*      bcnt     = (int*)alloc(MAXB * 4);
    int*      bbase    = (int*)alloc((MAXB + 1) * 4);
    int*      gcur     = (int*)alloc(MAXB * 4);
    int*      ssrc     = (int*)alloc((size_t)E * 4);
    _Float16* xl       = (_Float16*)alloc((size_t)N * 128 * 2);
    _Float16* xr       = (_Float16*)alloc((size_t)N * 128 * 2);
    _Float16* h0       = (_Float16*)alloc((size_t)N * 128 * 2);
    _Float16* gb       = (_Float16*)alloc((size_t)N * 128 * 2);
    _Float16* Wt0      = (_Float16*)alloc((size_t)256 * 256 * 2);
    _Float16* Wt1      = (_Float16*)alloc((size_t)256 * 128 * 2);
    _Float16* Wt2      = (_Float16*)alloc((size_t)128 * 128 * 2);

    // ebuf (binned packed edges, E*4 bytes) aliases gb: dead before gb's first
    // write (layer-1 agg), stream-ordered so no hazard.
    unsigned* ebuf = (unsigned*)gb;

    float* out = (float*)d_out;
    float* x_final = out;                      // N*64
    float* out1    = out + (size_t)N * 64;     // N*128
    float* g       = out + (size_t)N * 192;    // N*128

    const int nb = (N + 255) >> 8;
    const int nbk = (E + BIN_CHUNK - 1) / BIN_CHUNK;
    const int nch = (N + 2047) / 2048;

    // ---- CSR build (binned) ----
    hipMemsetAsync(bcnt, 0, MAXB * 4, stream);
    k_bhist<<<nbk, 256, 0, stream>>>(dst, bcnt, E);
    k_pscan<<<1, 512, 0, stream>>>(bcnt, bbase, gcur, bbase + nb, nb);
    k_bin<<<nbk, 256, 0, stream>>>(src, dst, gcur, ebuf, E);
    k_nhist<<<nb, 256, 0, stream>>>(ebuf, bbase, rowptr, N);
    k_scan1<<<nch, 256, 0, stream>>>(rowptr, chunkSum, N);
    k_pscan<<<1, 512, 0, stream>>>(chunkSum, chunkOff, nullptr, rowptr + N, nch);
    k_scan3<<<(N + 255) / 256, 256, 0, stream>>>(rowptr, chunkOff, N);
    k_bfill<<<nb, 256, 0, stream>>>(ebuf, bbase, rowptr, ssrc, N);

    // ---- weight prep (single launch, all layers) ----
    k_wprepAll<<<448, 256, 0, stream>>>(Wl0, Wr0, Wl1, Wr1, Wl2, Wr2, Wt0, Wt1, Wt2);

    const int gGrid = (N + 63) / 64;

    // ---- layer 0 ----
    k_gemmM<256, 256, true><<<gGrid, 256, 0, stream>>>(x, Wt0, b0, xl, xr, N);
    k_agg<128, 0><<<(N + 31) / 32, 256, 0, stream>>>((const half8*)xl, (const half8*)xr,
                                                     rowptr, ssrc, nullptr, nullptr, h0, N);

    // ---- layer 1 ----
    k_gemmM<128, 256, false><<<gGrid, 256, 0, stream>>>(h0, Wt1, b1, xl, xr, N);
    k_agg<128, 1><<<(N + 31) / 32, 256, 0, stream>>>((const half8*)xl, (const half8*)xr,
                                                     rowptr, ssrc, out1, g, gb, N);

    // ---- layer 2 ----
    k_gemmM<128, 128, false><<<gGrid, 256, 0, stream>>>(gb, Wt2, b2, xl, xr, N);
    k_agg<64, 2><<<(N + 63) / 64, 256, 0, stream>>>((const half8*)xl, (const half8*)xr,
                                                    rowptr, ssrc, x_final, nullptr, nullptr, N);
}

// Round 6
// 536.512 us; speedup vs baseline: 1.4895x; 1.0312x over previous
//
#include <hip/hip_runtime.h>
#include <stdint.h>

typedef __attribute__((ext_vector_type(4))) float f32x4;
typedef _Float16 half8 __attribute__((ext_vector_type(8)));
typedef _Float16 half4 __attribute__((ext_vector_type(4)));

// ---------------- CSR build via bucket binning ----------------

#define BIN_CHUNK 8192   // edges per block, 32/thread
#define MAXB 512         // >= nb = ceil(N/256)

__global__ __launch_bounds__(256) void k_bhist(const int* __restrict__ dst,
                                               int* __restrict__ bcnt, int E) {
    __shared__ int lh[MAXB];
    for (int i = threadIdx.x; i < MAXB; i += 256) lh[i] = 0;
    __syncthreads();
    const int base = blockIdx.x * BIN_CHUNK;
#pragma unroll 4
    for (int i = 0; i < BIN_CHUNK / 256; i++) {
        int e = base + i * 256 + threadIdx.x;
        if (e < E) atomicAdd(&lh[dst[e] >> 8], 1);
    }
    __syncthreads();
    for (int i = threadIdx.x; i < MAXB; i += 256)
        if (lh[i]) atomicAdd(&bcnt[i], lh[i]);
}

// Parallel exclusive scan over n<=2048 ints, single block of 512 threads.
// out0 = exclusive prefix; out1 (optional) = copy; tot (optional) = total sum.
__global__ __launch_bounds__(512) void k_pscan(const int* __restrict__ in,
                                               int* __restrict__ out0,
                                               int* __restrict__ out1,
                                               int* __restrict__ tot, int n) {
    __shared__ int sh[512];
    const int t = threadIdx.x;
    int v[4];
    int s = 0;
#pragma unroll
    for (int i = 0; i < 4; i++) {
        int idx = t * 4 + i;
        v[i] = (idx < n) ? in[idx] : 0;
        s += v[i];
    }
    sh[t] = s;
    __syncthreads();
    for (int off = 1; off < 512; off <<= 1) {
        int add = (t >= off) ? sh[t - off] : 0;
        __syncthreads();
        sh[t] += add;
        __syncthreads();
    }
    int excl = sh[t] - s;
#pragma unroll
    for (int i = 0; i < 4; i++) {
        int idx = t * 4 + i;
        if (idx < n) {
            out0[idx] = excl;
            if (out1) out1[idx] = excl;
        }
        excl += v[i];
    }
    if (t == 511 && tot) *tot = sh[511];
}

__global__ __launch_bounds__(256) void k_bin(const int* __restrict__ src,
                                             const int* __restrict__ dst,
                                             int* __restrict__ gcur,
                                             unsigned* __restrict__ ebuf, int E) {
    __shared__ int lh[MAXB];
    __shared__ int lcur[MAXB];
    for (int i = threadIdx.x; i < MAXB; i += 256) lh[i] = 0;
    __syncthreads();
    const int base = blockIdx.x * BIN_CHUNK;
#pragma unroll 4
    for (int i = 0; i < BIN_CHUNK / 256; i++) {
        int e = base + i * 256 + threadIdx.x;
        if (e < E) atomicAdd(&lh[dst[e] >> 8], 1);
    }
    __syncthreads();
    for (int i = threadIdx.x; i < MAXB; i += 256)
        lcur[i] = lh[i] ? atomicAdd(&gcur[i], lh[i]) : 0;
    __syncthreads();
#pragma unroll 4
    for (int i = 0; i < BIN_CHUNK / 256; i++) {
        int e = base + i * 256 + threadIdx.x;
        if (e < E) {
            int d = dst[e];
            int pos = atomicAdd(&lcur[d >> 8], 1);
            ebuf[pos] = (unsigned)src[e] | ((unsigned)(d & 255) << 24);
        }
    }
}

// Fused per-bucket CSR finalize: degree count (LDS) -> 256-wide LDS scan ->
// rowptr = bbase[b] + local exclusive prefix -> scatter ssrc via LDS cursors.
// Replaces k_nhist + k_scan1 + k_pscan#2 + k_scan3 + k_bfill; second ebuf
// pass is L2-hot (16KB/bucket). Last bucket's thread at n==N writes rowptr[N]=E.
__global__ __launch_bounds__(256) void k_csr(const unsigned* __restrict__ ebuf,
                                             const int* __restrict__ bbase,
                                             int* __restrict__ rowptr,
                                             int* __restrict__ ssrc, int N) {
    __shared__ int cnt[256];
    __shared__ int sh[256];
    __shared__ int lc[256];
    const int t = threadIdx.x;
    const int b = blockIdx.x;
    cnt[t] = 0;
    __syncthreads();
    const int lo = bbase[b], hi = bbase[b + 1];
    for (int e = lo + t; e < hi; e += 256)
        atomicAdd(&cnt[ebuf[e] >> 24], 1);
    __syncthreads();
    const int myc = cnt[t];
    sh[t] = myc;
    __syncthreads();
    for (int off = 1; off < 256; off <<= 1) {
        int add = (t >= off) ? sh[t - off] : 0;
        __syncthreads();
        sh[t] += add;
        __syncthreads();
    }
    const int base = lo + (sh[t] - myc);   // bbase[b] + exclusive prefix
    const int n = (b << 8) + t;
    if (n <= N) rowptr[n] = base;          // n==N (last bucket) -> rowptr[N]=E
    lc[t] = base;
    __syncthreads();
    for (int e = lo + t; e < hi; e += 256) {
        unsigned v = ebuf[e];
        int pos = atomicAdd(&lc[v >> 24], 1);
        ssrc[pos] = (int)(v & 0xFFFFFFu);
    }
}

// ---------------- weight prep (all three layers, one launch) ----------------
// Wt[(k>>5)*(NCOLT*32) + n*32 + (k&31)] = f16( n<NCOL ? Wl[k][n] : Wr[k][n-NCOL] )

template <int K, int NCOLT>
__device__ inline void wprep_one(const float* __restrict__ Wl, const float* __restrict__ Wr,
                                 _Float16* __restrict__ Wt, int i) {
    constexpr int NCOL = NCOLT / 2;
    int n = i / K, k = i - n * K;
    float v = (n < NCOL) ? Wl[(size_t)k * NCOL + n] : Wr[(size_t)k * NCOL + (n - NCOL)];
    Wt[(size_t)(k >> 5) * (NCOLT * 32) + n * 32 + (k & 31)] = (_Float16)v;
}

__global__ __launch_bounds__(256) void k_wprepAll(
    const float* __restrict__ Wl0, const float* __restrict__ Wr0,
    const float* __restrict__ Wl1, const float* __restrict__ Wr1,
    const float* __restrict__ Wl2, const float* __restrict__ Wr2,
    _Float16* __restrict__ Wt0, _Float16* __restrict__ Wt1, _Float16* __restrict__ Wt2) {
    int i = blockIdx.x * 256 + threadIdx.x;
    if (i < 65536) wprep_one<256, 256>(Wl0, Wr0, Wt0, i);
    else if (i < 98304) wprep_one<128, 256>(Wl1, Wr1, Wt1, i - 65536);
    else if (i < 114688) wprep_one<128, 128>(Wl2, Wr2, Wt2, i - 98304);
}

// ---------------- MFMA GEMM: [Cl|Cr] = A @ [Wl|Wr] ----------------

template <int K, int NCOLT, bool AF32>
__global__ __launch_bounds__(256) void k_gemmM(const void* __restrict__ Av,
                                               const _Float16* __restrict__ Wt,
                                               const float* __restrict__ bias,
                                               _Float16* __restrict__ Cl,
                                               _Float16* __restrict__ Cr, int M) {
    constexpr int NCOL = NCOLT / 2;
    constexpr int WC = NCOLT / 4;
    constexpr int NT = WC / 16;
    constexpr int AS = K + 8;
    constexpr int CS = NCOLT + 8;
    constexpr int MAXS = (K > NCOLT ? K : NCOLT) + 8;
    __shared__ _Float16 sh[64 * MAXS];

    const int tid = threadIdx.x;
    const int lane = tid & 63;
    const int wave = tid >> 6;
    const int quad = lane >> 4;
    const int l16 = lane & 15;
    const int m0 = blockIdx.x * 64;
    const int colbase = wave * WC;

    if (AF32) {
        const float* A = (const float*)Av;
#pragma unroll
        for (int i = 0; i < K / 16; i++) {
            int off = i * 1024 + tid * 4;
            int row = off / K, col = off % K;
            f32x4 u = {0.f, 0.f, 0.f, 0.f};
            if (m0 + row < M) u = *(const f32x4*)(A + (size_t)(m0 + row) * K + col);
            half4 h = {(_Float16)u[0], (_Float16)u[1], (_Float16)u[2], (_Float16)u[3]};
            *(half4*)(sh + row * AS + col) = h;
        }
    } else {
        const _Float16* A = (const _Float16*)Av;
#pragma unroll
        for (int i = 0; i < K / 32; i++) {
            int off = i * 2048 + tid * 8;
            int row = off / K, col = off % K;
            half8 u = {0, 0, 0, 0, 0, 0, 0, 0};
            if (m0 + row < M) u = *(const half8*)(A + (size_t)(m0 + row) * K + col);
            *(half8*)(sh + row * AS + col) = u;
        }
    }
    __syncthreads();

    f32x4 acc[4][NT];
#pragma unroll
    for (int rg = 0; rg < 4; rg++)
#pragma unroll
        for (int t = 0; t < NT; t++) acc[rg][t] = (f32x4){0.f, 0.f, 0.f, 0.f};

#pragma unroll
    for (int k0 = 0; k0 < K; k0 += 32) {
        half8 a[4];
#pragma unroll
        for (int rg = 0; rg < 4; rg++)
            a[rg] = *(const half8*)(sh + (rg * 16 + l16) * AS + k0 + quad * 8);
        half8 b[NT];
        const _Float16* Wk = Wt + (size_t)(k0 >> 5) * (NCOLT * 32);
#pragma unroll
        for (int t = 0; t < NT; t++)
            b[t] = *(const half8*)(Wk + (colbase + t * 16 + l16) * 32 + quad * 8);
#pragma unroll
        for (int rg = 0; rg < 4; rg++)
#pragma unroll
            for (int t = 0; t < NT; t++)
                acc[rg][t] = __builtin_amdgcn_mfma_f32_16x16x32_f16(b[t], a[rg], acc[rg][t], 0, 0, 0);
    }

    __syncthreads();

#pragma unroll
    for (int t = 0; t < NT; t++) {
        int c0 = colbase + t * 16 + quad * 4;
        f32x4 bv = {0.f, 0.f, 0.f, 0.f};
        if (c0 >= NCOL) bv = *(const f32x4*)(bias + (c0 - NCOL));
#pragma unroll
        for (int rg = 0; rg < 4; rg++) {
            half4 h = {(_Float16)(acc[rg][t][0] + bv[0]), (_Float16)(acc[rg][t][1] + bv[1]),
                       (_Float16)(acc[rg][t][2] + bv[2]), (_Float16)(acc[rg][t][3] + bv[3])};
            *(half4*)(sh + (rg * 16 + l16) * CS + c0) = h;
        }
    }
    __syncthreads();

#pragma unroll
    for (int i = 0; i < (64 * NCOL) / 2048; i++) {
        int off = i * 2048 + tid * 8;
        int row = off / NCOL, col = off % NCOL;
        if (m0 + row < M) {
            *(half8*)(Cl + (size_t)(m0 + row) * NCOL + col) = *(const half8*)(sh + row * CS + col);
            *(half8*)(Cr + (size_t)(m0 + row) * NCOL + col) = *(const half8*)(sh + row * CS + NCOL + col);
        }
    }
}

// ---------------- aggregation (round-2 structure, 8-deep gather unroll) ----------------
// Thread-group owns one node (16 ch/lane). 8-edge unroll => 16 b128 gathers in
// flight per lane (tests MLP-limited vs service-rate-limited hypothesis; R3/R4
// ruled out balance). FETCH is at the unique-line floor already.

template <int COUT, int MODE>
__global__ __launch_bounds__(256) void k_agg(const half8* __restrict__ xl,
                                             const half8* __restrict__ xr,
                                             const int* __restrict__ rowptr,
                                             const int* __restrict__ ssrc,
                                             float* __restrict__ outF1,
                                             float* __restrict__ outF2,
                                             _Float16* __restrict__ outH, int N) {
    constexpr int LPN = COUT / 16;
    constexpr int NPB = 256 / LPN;
    constexpr int C8 = COUT / 8;
    const int tid = threadIdx.x;
    const int c = tid % LPN;
    const int n = blockIdx.x * NPB + tid / LPN;
    if (n >= N) return;

    const int rp0 = rowptr[n];
    const int rp1 = rowptr[n + 1];
    float acc[16];
#pragma unroll
    for (int i = 0; i < 16; i++) acc[i] = 0.f;

    const size_t cb = (size_t)c * 2;
    int e = rp0;
    for (; e + 7 < rp1; e += 8) {
        int s[8];
#pragma unroll
        for (int u = 0; u < 8; u++) s[u] = ssrc[e + u];
        half8 va[8], vb[8];
#pragma unroll
        for (int u = 0; u < 8; u++) {
            const half8* p = xl + (size_t)s[u] * C8 + cb;
            va[u] = p[0];
            vb[u] = p[1];
        }
#pragma unroll
        for (int u = 0; u < 8; u++)
#pragma unroll
            for (int i = 0; i < 8; i++) {
                acc[i] += (float)va[u][i];
                acc[8 + i] += (float)vb[u][i];
            }
    }
    for (; e + 3 < rp1; e += 4) {
        int s0 = ssrc[e], s1 = ssrc[e + 1], s2 = ssrc[e + 2], s3 = ssrc[e + 3];
        half8 v0a = xl[(size_t)s0 * C8 + cb], v0b = xl[(size_t)s0 * C8 + cb + 1];
        half8 v1a = xl[(size_t)s1 * C8 + cb], v1b = xl[(size_t)s1 * C8 + cb + 1];
        half8 v2a = xl[(size_t)s2 * C8 + cb], v2b = xl[(size_t)s2 * C8 + cb + 1];
        half8 v3a = xl[(size_t)s3 * C8 + cb], v3b = xl[(size_t)s3 * C8 + cb + 1];
#pragma unroll
        for (int i = 0; i < 8; i++) {
            acc[i] += (float)v0a[i] + (float)v1a[i] + (float)v2a[i] + (float)v3a[i];
            acc[8 + i] += (float)v0b[i] + (float)v1b[i] + (float)v2b[i] + (float)v3b[i];
        }
    }
    for (; e < rp1; e++) {
        int s = ssrc[e];
        half8 va = xl[(size_t)s * C8 + cb], vb = xl[(size_t)s * C8 + cb + 1];
#pragma unroll
        for (int i = 0; i < 8; i++) {
            acc[i] += (float)va[i];
            acc[8 + i] += (float)vb[i];
        }
    }

    const int deg = rp1 - rp0;
    const float scale = 1.0f / (float)(deg > 1 ? deg : 1);
    half8 x0 = xr[(size_t)n * C8 + cb];
    half8 x1 = xr[(size_t)n * C8 + cb + 1];
    float res[16];
#pragma unroll
    for (int i = 0; i < 8; i++) {
        res[i] = acc[i] * scale + (float)x0[i];
        res[8 + i] = acc[8 + i] * scale + (float)x1[i];
    }

    const size_t ob = (size_t)n * COUT + (size_t)c * 16;
    if (MODE == 0) {
        half8 h0v, h1v;
#pragma unroll
        for (int i = 0; i < 8; i++) {
            h0v[i] = (_Float16)(res[i] > 0.f ? res[i] : 0.f);
            h1v[i] = (_Float16)(res[8 + i] > 0.f ? res[8 + i] : 0.f);
        }
        *(half8*)(outH + ob) = h0v;
        *(half8*)(outH + ob + 8) = h1v;
    } else if (MODE == 1) {
#pragma unroll
        for (int q = 0; q < 4; q++) {
            f32x4 v = {res[q * 4], res[q * 4 + 1], res[q * 4 + 2], res[q * 4 + 3]};
            *(f32x4*)(outF1 + ob + q * 4) = v;
            f32x4 z = {v[0] > 0.f ? v[0] : 0.f, v[1] > 0.f ? v[1] : 0.f,
                       v[2] > 0.f ? v[2] : 0.f, v[3] > 0.f ? v[3] : 0.f};
            *(f32x4*)(outF2 + ob + q * 4) = z;
        }
        half8 h0v, h1v;
#pragma unroll
        for (int i = 0; i < 8; i++) {
            h0v[i] = (_Float16)(res[i] > 0.f ? res[i] : 0.f);
            h1v[i] = (_Float16)(res[8 + i] > 0.f ? res[8 + i] : 0.f);
        }
        *(half8*)(outH + ob) = h0v;
        *(half8*)(outH + ob + 8) = h1v;
    } else {
#pragma unroll
        for (int q = 0; q < 4; q++) {
            f32x4 v = {res[q * 4], res[q * 4 + 1], res[q * 4 + 2], res[q * 4 + 3]};
            *(f32x4*)(outF1 + ob + q * 4) = v;
        }
    }
}

// ---------------- launch ----------------

extern "C" void kernel_launch(void* const* d_in, const int* in_sizes, int n_in,
                              void* d_out, int out_size, void* d_ws, size_t ws_size,
                              hipStream_t stream) {
    const float* x   = (const float*)d_in[0];
    const int*   ei  = (const int*)d_in[1];
    const float* Wl0 = (const float*)d_in[2];
    const float* Wr0 = (const float*)d_in[3];
    const float* b0  = (const float*)d_in[4];
    const float* Wl1 = (const float*)d_in[5];
    const float* Wr1 = (const float*)d_in[6];
    const float* b1  = (const float*)d_in[7];
    const float* Wl2 = (const float*)d_in[8];
    const float* Wr2 = (const float*)d_in[9];
    const float* b2  = (const float*)d_in[10];

    const int N = in_sizes[0] / 256;   // 100000
    const int E = in_sizes[1] / 2;     // 1600000
    const int* src = ei;
    const int* dst = ei + E;

    char* p = (char*)d_ws;
    auto alloc = [&](size_t bytes) -> void* {
        void* r = (void*)p;
        p += (bytes + 255) & ~(size_t)255;
        return r;
    };
    int*      rowptr   = (int*)alloc((size_t)(N + 1) * 4);
    int*      bcnt     = (int*)alloc(MAXB * 4);
    int*      bbase    = (int*)alloc((MAXB + 1) * 4);
    int*      gcur     = (int*)alloc(MAXB * 4);
    int*      ssrc     = (int*)alloc((size_t)E * 4);
    _Float16* xl       = (_Float16*)alloc((size_t)N * 128 * 2);
    _Float16* xr       = (_Float16*)alloc((size_t)N * 128 * 2);
    _Float16* h0       = (_Float16*)alloc((size_t)N * 128 * 2);
    _Float16* gb       = (_Float16*)alloc((size_t)N * 128 * 2);
    _Float16* Wt0      = (_Float16*)alloc((size_t)256 * 256 * 2);
    _Float16* Wt1      = (_Float16*)alloc((size_t)256 * 128 * 2);
    _Float16* Wt2      = (_Float16*)alloc((size_t)128 * 128 * 2);

    // ebuf (binned packed edges, E*4 bytes) aliases gb: dead before gb's first
    // write (layer-1 agg), stream-ordered so no hazard.
    unsigned* ebuf = (unsigned*)gb;

    float* out = (float*)d_out;
    float* x_final = out;                      // N*64
    float* out1    = out + (size_t)N * 64;     // N*128
    float* g       = out + (size_t)N * 192;    // N*128

    const int nb = (N + 255) >> 8;
    const int nbk = (E + BIN_CHUNK - 1) / BIN_CHUNK;

    // ---- CSR build (binned, fused finalize) ----
    hipMemsetAsync(bcnt, 0, MAXB * 4, stream);
    k_bhist<<<nbk, 256, 0, stream>>>(dst, bcnt, E);
    k_pscan<<<1, 512, 0, stream>>>(bcnt, bbase, gcur, bbase + nb, nb);
    k_bin<<<nbk, 256, 0, stream>>>(src, dst, gcur, ebuf, E);
    k_csr<<<nb, 256, 0, stream>>>(ebuf, bbase, rowptr, ssrc, N);

    // ---- weight prep (single launch, all layers) ----
    k_wprepAll<<<448, 256, 0, stream>>>(Wl0, Wr0, Wl1, Wr1, Wl2, Wr2, Wt0, Wt1, Wt2);

    const int gGrid = (N + 63) / 64;

    // ---- layer 0 ----
    k_gemmM<256, 256, true><<<gGrid, 256, 0, stream>>>(x, Wt0, b0, xl, xr, N);
    k_agg<128, 0><<<(N + 31) / 32, 256, 0, stream>>>((const half8*)xl, (const half8*)xr,
                                                     rowptr, ssrc, nullptr, nullptr, h0, N);

    // ---- layer 1 ----
    k_gemmM<128, 256, false><<<gGrid, 256, 0, stream>>>(h0, Wt1, b1, xl, xr, N);
    k_agg<128, 1><<<(N + 31) / 32, 256, 0, stream>>>((const half8*)xl, (const half8*)xr,
                                                     rowptr, ssrc, out1, g, gb, N);

    // ---- layer 2 ----
    k_gemmM<128, 128, false><<<gGrid, 256, 0, stream>>>(gb, Wt2, b2, xl, xr, N);
    k_agg<64, 2><<<(N + 63) / 64, 256, 0, stream>>>((const half8*)xl, (const half8*)xr,
                                                    rowptr, ssrc, x_final, nullptr, nullptr, N);
}

// Round 7
// 513.642 us; speedup vs baseline: 1.5558x; 1.0445x over previous
//
#include <hip/hip_runtime.h>
#include <stdint.h>

typedef __attribute__((ext_vector_type(4))) float f32x4;
typedef _Float16 half8 __attribute__((ext_vector_type(8)));
typedef _Float16 half4 __attribute__((ext_vector_type(4)));

// ---------------- CSR build via bucket binning ----------------

#define BIN_CHUNK 8192   // edges per block, 32/thread
#define MAXB 512         // >= nb = ceil(N/256)

// ---------------- weight prep (device body) ----------------
// Wt[(k>>5)*(NCOLT*32) + n*32 + (k&31)] = f16( n<NCOL ? Wl[k][n] : Wr[k][n-NCOL] )

template <int K, int NCOLT>
__device__ inline void wprep_one(const float* __restrict__ Wl, const float* __restrict__ Wr,
                                 _Float16* __restrict__ Wt, int i) {
    constexpr int NCOL = NCOLT / 2;
    int n = i / K, k = i - n * K;
    float v = (n < NCOL) ? Wl[(size_t)k * NCOL + n] : Wr[(size_t)k * NCOL + (n - NCOL)];
    Wt[(size_t)(k >> 5) * (NCOLT * 32) + n * 32 + (k & 31)] = (_Float16)v;
}

// Fused: blocks [0,nbk) = dst-bucket histogram; blocks [nbk, nbk+448) = weight prep.
__global__ __launch_bounds__(256) void k_bhistW(
    const int* __restrict__ dst, int* __restrict__ bcnt, int E, int nbk,
    const float* __restrict__ Wl0, const float* __restrict__ Wr0,
    const float* __restrict__ Wl1, const float* __restrict__ Wr1,
    const float* __restrict__ Wl2, const float* __restrict__ Wr2,
    _Float16* __restrict__ Wt0, _Float16* __restrict__ Wt1, _Float16* __restrict__ Wt2) {
    if ((int)blockIdx.x < nbk) {
        __shared__ int lh[MAXB];
        for (int i = threadIdx.x; i < MAXB; i += 256) lh[i] = 0;
        __syncthreads();
        const int base = blockIdx.x * BIN_CHUNK;
#pragma unroll 4
        for (int i = 0; i < BIN_CHUNK / 256; i++) {
            int e = base + i * 256 + threadIdx.x;
            if (e < E) atomicAdd(&lh[dst[e] >> 8], 1);
        }
        __syncthreads();
        for (int i = threadIdx.x; i < MAXB; i += 256)
            if (lh[i]) atomicAdd(&bcnt[i], lh[i]);
    } else {
        int i = (blockIdx.x - nbk) * 256 + threadIdx.x;
        if (i < 65536) wprep_one<256, 256>(Wl0, Wr0, Wt0, i);
        else if (i < 98304) wprep_one<128, 256>(Wl1, Wr1, Wt1, i - 65536);
        else if (i < 114688) wprep_one<128, 128>(Wl2, Wr2, Wt2, i - 98304);
    }
}

// Parallel exclusive scan over n<=2048 ints, single block of 512 threads.
__global__ __launch_bounds__(512) void k_pscan(const int* __restrict__ in,
                                               int* __restrict__ out0,
                                               int* __restrict__ out1,
                                               int* __restrict__ tot, int n) {
    __shared__ int sh[512];
    const int t = threadIdx.x;
    int v[4];
    int s = 0;
#pragma unroll
    for (int i = 0; i < 4; i++) {
        int idx = t * 4 + i;
        v[i] = (idx < n) ? in[idx] : 0;
        s += v[i];
    }
    sh[t] = s;
    __syncthreads();
    for (int off = 1; off < 512; off <<= 1) {
        int add = (t >= off) ? sh[t - off] : 0;
        __syncthreads();
        sh[t] += add;
        __syncthreads();
    }
    int excl = sh[t] - s;
#pragma unroll
    for (int i = 0; i < 4; i++) {
        int idx = t * 4 + i;
        if (idx < n) {
            out0[idx] = excl;
            if (out1) out1[idx] = excl;
        }
        excl += v[i];
    }
    if (t == 511 && tot) *tot = sh[511];
}

// ---------------- bin (device body) ----------------

__device__ inline void bin_body(const int* __restrict__ src, const int* __restrict__ dst,
                                int* __restrict__ gcur, unsigned* __restrict__ ebuf,
                                int E, int bid, int* __restrict__ smem) {
    int* lh = smem;          // [MAXB]
    int* lcur = smem + MAXB; // [MAXB]
    for (int i = threadIdx.x; i < MAXB; i += 256) lh[i] = 0;
    __syncthreads();
    const int base = bid * BIN_CHUNK;
#pragma unroll 4
    for (int i = 0; i < BIN_CHUNK / 256; i++) {
        int e = base + i * 256 + threadIdx.x;
        if (e < E) atomicAdd(&lh[dst[e] >> 8], 1);
    }
    __syncthreads();
    for (int i = threadIdx.x; i < MAXB; i += 256)
        lcur[i] = lh[i] ? atomicAdd(&gcur[i], lh[i]) : 0;
    __syncthreads();
#pragma unroll 4
    for (int i = 0; i < BIN_CHUNK / 256; i++) {
        int e = base + i * 256 + threadIdx.x;
        if (e < E) {
            int d = dst[e];
            int pos = atomicAdd(&lcur[d >> 8], 1);
            ebuf[pos] = (unsigned)src[e] | ((unsigned)(d & 255) << 24);
        }
    }
}

// ---------------- MFMA GEMM body: [Cl|Cr] = A @ [Wl|Wr] ----------------

template <int K, int NCOLT, bool AF32>
__device__ inline void gemm_body(const void* __restrict__ Av,
                                 const _Float16* __restrict__ Wt,
                                 const float* __restrict__ bias,
                                 _Float16* __restrict__ Cl,
                                 _Float16* __restrict__ Cr, int M, int bid,
                                 _Float16* __restrict__ sh) {
    constexpr int NCOL = NCOLT / 2;
    constexpr int WC = NCOLT / 4;
    constexpr int NT = WC / 16;
    constexpr int AS = K + 8;
    constexpr int CS = NCOLT + 8;

    const int tid = threadIdx.x;
    const int lane = tid & 63;
    const int wave = tid >> 6;
    const int quad = lane >> 4;
    const int l16 = lane & 15;
    const int m0 = bid * 64;
    const int colbase = wave * WC;

    if (AF32) {
        const float* A = (const float*)Av;
#pragma unroll
        for (int i = 0; i < K / 16; i++) {
            int off = i * 1024 + tid * 4;
            int row = off / K, col = off % K;
            f32x4 u = {0.f, 0.f, 0.f, 0.f};
            if (m0 + row < M) u = *(const f32x4*)(A + (size_t)(m0 + row) * K + col);
            half4 h = {(_Float16)u[0], (_Float16)u[1], (_Float16)u[2], (_Float16)u[3]};
            *(half4*)(sh + row * AS + col) = h;
        }
    } else {
        const _Float16* A = (const _Float16*)Av;
#pragma unroll
        for (int i = 0; i < K / 32; i++) {
            int off = i * 2048 + tid * 8;
            int row = off / K, col = off % K;
            half8 u = {0, 0, 0, 0, 0, 0, 0, 0};
            if (m0 + row < M) u = *(const half8*)(A + (size_t)(m0 + row) * K + col);
            *(half8*)(sh + row * AS + col) = u;
        }
    }
    __syncthreads();

    f32x4 acc[4][NT];
#pragma unroll
    for (int rg = 0; rg < 4; rg++)
#pragma unroll
        for (int t = 0; t < NT; t++) acc[rg][t] = (f32x4){0.f, 0.f, 0.f, 0.f};

#pragma unroll
    for (int k0 = 0; k0 < K; k0 += 32) {
        half8 a[4];
#pragma unroll
        for (int rg = 0; rg < 4; rg++)
            a[rg] = *(const half8*)(sh + (rg * 16 + l16) * AS + k0 + quad * 8);
        half8 b[NT];
        const _Float16* Wk = Wt + (size_t)(k0 >> 5) * (NCOLT * 32);
#pragma unroll
        for (int t = 0; t < NT; t++)
            b[t] = *(const half8*)(Wk + (colbase + t * 16 + l16) * 32 + quad * 8);
#pragma unroll
        for (int rg = 0; rg < 4; rg++)
#pragma unroll
            for (int t = 0; t < NT; t++)
                acc[rg][t] = __builtin_amdgcn_mfma_f32_16x16x32_f16(b[t], a[rg], acc[rg][t], 0, 0, 0);
    }

    __syncthreads();

#pragma unroll
    for (int t = 0; t < NT; t++) {
        int c0 = colbase + t * 16 + quad * 4;
        f32x4 bv = {0.f, 0.f, 0.f, 0.f};
        if (c0 >= NCOL) bv = *(const f32x4*)(bias + (c0 - NCOL));
#pragma unroll
        for (int rg = 0; rg < 4; rg++) {
            half4 h = {(_Float16)(acc[rg][t][0] + bv[0]), (_Float16)(acc[rg][t][1] + bv[1]),
                       (_Float16)(acc[rg][t][2] + bv[2]), (_Float16)(acc[rg][t][3] + bv[3])};
            *(half4*)(sh + (rg * 16 + l16) * CS + c0) = h;
        }
    }
    __syncthreads();

#pragma unroll
    for (int i = 0; i < (64 * NCOL) / 2048; i++) {
        int off = i * 2048 + tid * 8;
        int row = off / NCOL, col = off % NCOL;
        if (m0 + row < M) {
            *(half8*)(Cl + (size_t)(m0 + row) * NCOL + col) = *(const half8*)(sh + row * CS + col);
            *(half8*)(Cr + (size_t)(m0 + row) * NCOL + col) = *(const half8*)(sh + row * CS + NCOL + col);
        }
    }
}

template <int K, int NCOLT, bool AF32>
__global__ __launch_bounds__(256) void k_gemmM(const void* __restrict__ Av,
                                               const _Float16* __restrict__ Wt,
                                               const float* __restrict__ bias,
                                               _Float16* __restrict__ Cl,
                                               _Float16* __restrict__ Cr, int M) {
    constexpr int MAXS = (K > NCOLT ? K : NCOLT) + 8;
    __shared__ _Float16 sh[64 * MAXS];
    gemm_body<K, NCOLT, AF32>(Av, Wt, bias, Cl, Cr, M, blockIdx.x, sh);
}

// Fused: blocks [0,nbk) = edge binning; blocks [nbk, nbk+gGrid) = layer-0 GEMM.
// Independent dataflows co-scheduled on one dispatch (latency-bound binning
// overlaps compute-bound MFMA).
__global__ __launch_bounds__(256) void k_binGemm0(
    const int* __restrict__ src, const int* __restrict__ dst,
    int* __restrict__ gcur, unsigned* __restrict__ ebuf, int E, int nbk,
    const float* __restrict__ x, const _Float16* __restrict__ Wt0,
    const float* __restrict__ b0, _Float16* __restrict__ xl,
    _Float16* __restrict__ xr, int M) {
    __shared__ __align__(16) char smem[64 * 264 * 2];  // max(gemm 33792B, bin 4096B)
    if ((int)blockIdx.x < nbk) {
        bin_body(src, dst, gcur, ebuf, E, blockIdx.x, (int*)smem);
    } else {
        gemm_body<256, 256, true>(x, Wt0, b0, xl, xr, M, blockIdx.x - nbk,
                                  (_Float16*)smem);
    }
}

// Fused per-bucket CSR finalize: degree count (LDS) -> 256-wide LDS scan ->
// rowptr = bbase[b] + local exclusive prefix -> scatter ssrc via LDS cursors.
__global__ __launch_bounds__(256) void k_csr(const unsigned* __restrict__ ebuf,
                                             const int* __restrict__ bbase,
                                             int* __restrict__ rowptr,
                                             int* __restrict__ ssrc, int N) {
    __shared__ int cnt[256];
    __shared__ int sh[256];
    __shared__ int lc[256];
    const int t = threadIdx.x;
    const int b = blockIdx.x;
    cnt[t] = 0;
    __syncthreads();
    const int lo = bbase[b], hi = bbase[b + 1];
    for (int e = lo + t; e < hi; e += 256)
        atomicAdd(&cnt[ebuf[e] >> 24], 1);
    __syncthreads();
    const int myc = cnt[t];
    sh[t] = myc;
    __syncthreads();
    for (int off = 1; off < 256; off <<= 1) {
        int add = (t >= off) ? sh[t - off] : 0;
        __syncthreads();
        sh[t] += add;
        __syncthreads();
    }
    const int base = lo + (sh[t] - myc);   // bbase[b] + exclusive prefix
    const int n = (b << 8) + t;
    if (n <= N) rowptr[n] = base;          // n==N (last bucket) -> rowptr[N]=E
    lc[t] = base;
    __syncthreads();
    for (int e = lo + t; e < hi; e += 256) {
        unsigned v = ebuf[e];
        int pos = atomicAdd(&lc[v >> 24], 1);
        ssrc[pos] = (int)(v & 0xFFFFFFu);
    }
}

// ---------------- aggregation (round-5 proven structure) ----------------
// Thread-group owns one node (16 ch/lane), 4-edge unroll (8 b128 gathers in
// flight). Measured ceiling: ~3.75 TB/s mixed, FETCH at unique-line floor.
// Do NOT deepen unroll (R6: 80 VGPR, occ 41->26%, rate dropped) or rebalance
// (R3/R4: both regressed).

template <int COUT, int MODE>
__global__ __launch_bounds__(256) void k_agg(const half8* __restrict__ xl,
                                             const half8* __restrict__ xr,
                                             const int* __restrict__ rowptr,
                                             const int* __restrict__ ssrc,
                                             float* __restrict__ outF1,
                                             float* __restrict__ outF2,
                                             _Float16* __restrict__ outH, int N) {
    constexpr int LPN = COUT / 16;
    constexpr int NPB = 256 / LPN;
    constexpr int C8 = COUT / 8;
    const int tid = threadIdx.x;
    const int c = tid % LPN;
    const int n = blockIdx.x * NPB + tid / LPN;
    if (n >= N) return;

    const int rp0 = rowptr[n];
    const int rp1 = rowptr[n + 1];
    float acc[16];
#pragma unroll
    for (int i = 0; i < 16; i++) acc[i] = 0.f;

    const size_t cb = (size_t)c * 2;
    int e = rp0;
    for (; e + 3 < rp1; e += 4) {
        int s0 = ssrc[e], s1 = ssrc[e + 1], s2 = ssrc[e + 2], s3 = ssrc[e + 3];
        half8 v0a = xl[(size_t)s0 * C8 + cb], v0b = xl[(size_t)s0 * C8 + cb + 1];
        half8 v1a = xl[(size_t)s1 * C8 + cb], v1b = xl[(size_t)s1 * C8 + cb + 1];
        half8 v2a = xl[(size_t)s2 * C8 + cb], v2b = xl[(size_t)s2 * C8 + cb + 1];
        half8 v3a = xl[(size_t)s3 * C8 + cb], v3b = xl[(size_t)s3 * C8 + cb + 1];
#pragma unroll
        for (int i = 0; i < 8; i++) {
            acc[i] += (float)v0a[i] + (float)v1a[i] + (float)v2a[i] + (float)v3a[i];
            acc[8 + i] += (float)v0b[i] + (float)v1b[i] + (float)v2b[i] + (float)v3b[i];
        }
    }
    for (; e < rp1; e++) {
        int s = ssrc[e];
        half8 va = xl[(size_t)s * C8 + cb], vb = xl[(size_t)s * C8 + cb + 1];
#pragma unroll
        for (int i = 0; i < 8; i++) {
            acc[i] += (float)va[i];
            acc[8 + i] += (float)vb[i];
        }
    }

    const int deg = rp1 - rp0;
    const float scale = 1.0f / (float)(deg > 1 ? deg : 1);
    half8 x0 = xr[(size_t)n * C8 + cb];
    half8 x1 = xr[(size_t)n * C8 + cb + 1];
    float res[16];
#pragma unroll
    for (int i = 0; i < 8; i++) {
        res[i] = acc[i] * scale + (float)x0[i];
        res[8 + i] = acc[8 + i] * scale + (float)x1[i];
    }

    const size_t ob = (size_t)n * COUT + (size_t)c * 16;
    if (MODE == 0) {
        half8 h0v, h1v;
#pragma unroll
        for (int i = 0; i < 8; i++) {
            h0v[i] = (_Float16)(res[i] > 0.f ? res[i] : 0.f);
            h1v[i] = (_Float16)(res[8 + i] > 0.f ? res[8 + i] : 0.f);
        }
        *(half8*)(outH + ob) = h0v;
        *(half8*)(outH + ob + 8) = h1v;
    } else if (MODE == 1) {
#pragma unroll
        for (int q = 0; q < 4; q++) {
            f32x4 v = {res[q * 4], res[q * 4 + 1], res[q * 4 + 2], res[q * 4 + 3]};
            *(f32x4*)(outF1 + ob + q * 4) = v;
            f32x4 z = {v[0] > 0.f ? v[0] : 0.f, v[1] > 0.f ? v[1] : 0.f,
                       v[2] > 0.f ? v[2] : 0.f, v[3] > 0.f ? v[3] : 0.f};
            *(f32x4*)(outF2 + ob + q * 4) = z;
        }
        half8 h0v, h1v;
#pragma unroll
        for (int i = 0; i < 8; i++) {
            h0v[i] = (_Float16)(res[i] > 0.f ? res[i] : 0.f);
            h1v[i] = (_Float16)(res[8 + i] > 0.f ? res[8 + i] : 0.f);
        }
        *(half8*)(outH + ob) = h0v;
        *(half8*)(outH + ob + 8) = h1v;
    } else {
#pragma unroll
        for (int q = 0; q < 4; q++) {
            f32x4 v = {res[q * 4], res[q * 4 + 1], res[q * 4 + 2], res[q * 4 + 3]};
            *(f32x4*)(outF1 + ob + q * 4) = v;
        }
    }
}

// ---------------- launch ----------------

extern "C" void kernel_launch(void* const* d_in, const int* in_sizes, int n_in,
                              void* d_out, int out_size, void* d_ws, size_t ws_size,
                              hipStream_t stream) {
    const float* x   = (const float*)d_in[0];
    const int*   ei  = (const int*)d_in[1];
    const float* Wl0 = (const float*)d_in[2];
    const float* Wr0 = (const float*)d_in[3];
    const float* b0  = (const float*)d_in[4];
    const float* Wl1 = (const float*)d_in[5];
    const float* Wr1 = (const float*)d_in[6];
    const float* b1  = (const float*)d_in[7];
    const float* Wl2 = (const float*)d_in[8];
    const float* Wr2 = (const float*)d_in[9];
    const float* b2  = (const float*)d_in[10];

    const int N = in_sizes[0] / 256;   // 100000
    const int E = in_sizes[1] / 2;     // 1600000
    const int* src = ei;
    const int* dst = ei + E;

    char* p = (char*)d_ws;
    auto alloc = [&](size_t bytes) -> void* {
        void* r = (void*)p;
        p += (bytes + 255) & ~(size_t)255;
        return r;
    };
    int*      rowptr   = (int*)alloc((size_t)(N + 1) * 4);
    int*      bcnt     = (int*)alloc(MAXB * 4);
    int*      bbase    = (int*)alloc((MAXB + 1) * 4);
    int*      gcur     = (int*)alloc(MAXB * 4);
    int*      ssrc     = (int*)alloc((size_t)E * 4);
    _Float16* xl       = (_Float16*)alloc((size_t)N * 128 * 2);
    _Float16* xr       = (_Float16*)alloc((size_t)N * 128 * 2);
    _Float16* h0       = (_Float16*)alloc((size_t)N * 128 * 2);
    _Float16* gb       = (_Float16*)alloc((size_t)N * 128 * 2);
    _Float16* Wt0      = (_Float16*)alloc((size_t)256 * 256 * 2);
    _Float16* Wt1      = (_Float16*)alloc((size_t)256 * 128 * 2);
    _Float16* Wt2      = (_Float16*)alloc((size_t)128 * 128 * 2);

    // ebuf (binned packed edges, E*4 bytes) aliases gb: dead before gb's first
    // write (layer-1 agg), stream-ordered so no hazard.
    unsigned* ebuf = (unsigned*)gb;

    float* out = (float*)d_out;
    float* x_final = out;                      // N*64
    float* out1    = out + (size_t)N * 64;     // N*128
    float* g       = out + (size_t)N * 192;    // N*128

    const int nb = (N + 255) >> 8;
    const int nbk = (E + BIN_CHUNK - 1) / BIN_CHUNK;
    const int gGrid = (N + 63) / 64;

    // ---- CSR build overlapped with weight prep + layer-0 GEMM ----
    hipMemsetAsync(bcnt, 0, MAXB * 4, stream);
    k_bhistW<<<nbk + 448, 256, 0, stream>>>(dst, bcnt, E, nbk,
                                            Wl0, Wr0, Wl1, Wr1, Wl2, Wr2,
                                            Wt0, Wt1, Wt2);
    k_pscan<<<1, 512, 0, stream>>>(bcnt, bbase, gcur, bbase + nb, nb);
    k_binGemm0<<<nbk + gGrid, 256, 0, stream>>>(src, dst, gcur, ebuf, E, nbk,
                                                x, Wt0, b0, xl, xr, N);
    k_csr<<<nb, 256, 0, stream>>>(ebuf, bbase, rowptr, ssrc, N);

    // ---- layer 0 aggregation ----
    k_agg<128, 0><<<(N + 31) / 32, 256, 0, stream>>>((const half8*)xl, (const half8*)xr,
                                                     rowptr, ssrc, nullptr, nullptr, h0, N);

    // ---- layer 1 ----
    k_gemmM<128, 256, false><<<gGrid, 256, 0, stream>>>(h0, Wt1, b1, xl, xr, N);
    k_agg<128, 1><<<(N + 31) / 32, 256, 0, stream>>>((const half8*)xl, (const half8*)xr,
                                                     rowptr, ssrc, out1, g, gb, N);

    // ---- layer 2 ----
    k_gemmM<128, 128, false><<<gGrid, 256, 0, stream>>>(gb, Wt2, b2, xl, xr, N);
    k_agg<64, 2><<<(N + 63) / 64, 256, 0, stream>>>((const half8*)xl, (const half8*)xr,
                                                    rowptr, ssrc, x_final, nullptr, nullptr, N);
}

// Round 9
// 502.749 us; speedup vs baseline: 1.5895x; 1.0217x over previous
//
#include <hip/hip_runtime.h>
#include <stdint.h>

typedef __attribute__((ext_vector_type(4))) float f32x4;
typedef _Float16 half8 __attribute__((ext_vector_type(8)));
typedef _Float16 half4 __attribute__((ext_vector_type(4)));

// ---------------- CSR build via bucket binning ----------------

#define BIN_CHUNK 8192   // edges per block, 32/thread
#define MAXB 512         // >= nb = ceil(N/256)

// ---------------- weight prep (device body) ----------------
// Wt[(k>>5)*(NCOLT*32) + n*32 + (k&31)] = f16( n<NCOL ? Wl[k][n] : Wr[k][n-NCOL] )

template <int K, int NCOLT>
__device__ inline void wprep_one(const float* __restrict__ Wl, const float* __restrict__ Wr,
                                 _Float16* __restrict__ Wt, int i) {
    constexpr int NCOL = NCOLT / 2;
    int n = i / K, k = i - n * K;
    float v = (n < NCOL) ? Wl[(size_t)k * NCOL + n] : Wr[(size_t)k * NCOL + (n - NCOL)];
    Wt[(size_t)(k >> 5) * (NCOLT * 32) + n * 32 + (k & 31)] = (_Float16)v;
}

// Fused: blocks [0,nbk) = dst-bucket histogram; blocks [nbk, nbk+448) = weight prep.
__global__ __launch_bounds__(256) void k_bhistW(
    const int* __restrict__ dst, int* __restrict__ bcnt, int E, int nbk,
    const float* __restrict__ Wl0, const float* __restrict__ Wr0,
    const float* __restrict__ Wl1, const float* __restrict__ Wr1,
    const float* __restrict__ Wl2, const float* __restrict__ Wr2,
    _Float16* __restrict__ Wt0, _Float16* __restrict__ Wt1, _Float16* __restrict__ Wt2) {
    if ((int)blockIdx.x < nbk) {
        __shared__ int lh[MAXB];
        for (int i = threadIdx.x; i < MAXB; i += 256) lh[i] = 0;
        __syncthreads();
        const int base = blockIdx.x * BIN_CHUNK;
#pragma unroll 4
        for (int i = 0; i < BIN_CHUNK / 256; i++) {
            int e = base + i * 256 + threadIdx.x;
            if (e < E) atomicAdd(&lh[dst[e] >> 8], 1);
        }
        __syncthreads();
        for (int i = threadIdx.x; i < MAXB; i += 256)
            if (lh[i]) atomicAdd(&bcnt[i], lh[i]);
    } else {
        int i = (blockIdx.x - nbk) * 256 + threadIdx.x;
        if (i < 65536) wprep_one<256, 256>(Wl0, Wr0, Wt0, i);
        else if (i < 98304) wprep_one<128, 256>(Wl1, Wr1, Wt1, i - 65536);
        else if (i < 114688) wprep_one<128, 128>(Wl2, Wr2, Wt2, i - 98304);
    }
}

// Parallel exclusive scan over n<=2048 ints, single block of 512 threads.
__global__ __launch_bounds__(512) void k_pscan(const int* __restrict__ in,
                                               int* __restrict__ out0,
                                               int* __restrict__ out1,
                                               int* __restrict__ tot, int n) {
    __shared__ int sh[512];
    const int t = threadIdx.x;
    int v[4];
    int s = 0;
#pragma unroll
    for (int i = 0; i < 4; i++) {
        int idx = t * 4 + i;
        v[i] = (idx < n) ? in[idx] : 0;
        s += v[i];
    }
    sh[t] = s;
    __syncthreads();
    for (int off = 1; off < 512; off <<= 1) {
        int add = (t >= off) ? sh[t - off] : 0;
        __syncthreads();
        sh[t] += add;
        __syncthreads();
    }
    int excl = sh[t] - s;
#pragma unroll
    for (int i = 0; i < 4; i++) {
        int idx = t * 4 + i;
        if (idx < n) {
            out0[idx] = excl;
            if (out1) out1[idx] = excl;
        }
        excl += v[i];
    }
    if (t == 511 && tot) *tot = sh[511];
}

// ---------------- bin (device body) ----------------

__device__ inline void bin_body(const int* __restrict__ src, const int* __restrict__ dst,
                                int* __restrict__ gcur, unsigned* __restrict__ ebuf,
                                int E, int bid, int* __restrict__ smem) {
    int* lh = smem;          // [MAXB]
    int* lcur = smem + MAXB; // [MAXB]
    for (int i = threadIdx.x; i < MAXB; i += 256) lh[i] = 0;
    __syncthreads();
    const int base = bid * BIN_CHUNK;
#pragma unroll 4
    for (int i = 0; i < BIN_CHUNK / 256; i++) {
        int e = base + i * 256 + threadIdx.x;
        if (e < E) atomicAdd(&lh[dst[e] >> 8], 1);
    }
    __syncthreads();
    for (int i = threadIdx.x; i < MAXB; i += 256)
        lcur[i] = lh[i] ? atomicAdd(&gcur[i], lh[i]) : 0;
    __syncthreads();
#pragma unroll 4
    for (int i = 0; i < BIN_CHUNK / 256; i++) {
        int e = base + i * 256 + threadIdx.x;
        if (e < E) {
            int d = dst[e];
            int pos = atomicAdd(&lcur[d >> 8], 1);
            ebuf[pos] = (unsigned)src[e] | ((unsigned)(d & 255) << 24);
        }
    }
}

// ---------------- MFMA GEMM core (A-tile already in LDS) ----------------
// sh A-layout: sh[row*(K+8) + k], 64 rows. Reuses sh for the C-tile after a
// barrier. MFMA with swapped operands: acc[rg][t][r] = C[m0+rg*16+l16][c0+r].

template <int K, int NCOLT>
__device__ inline void gemm_core(_Float16* __restrict__ sh,
                                 const _Float16* __restrict__ Wt,
                                 const float* __restrict__ bias,
                                 _Float16* __restrict__ Cl,
                                 _Float16* __restrict__ Cr, int M, int bid) {
    constexpr int NCOL = NCOLT / 2;
    constexpr int WC = NCOLT / 4;
    constexpr int NT = WC / 16;
    constexpr int AS = K + 8;
    constexpr int CS = NCOLT + 8;

    const int tid = threadIdx.x;
    const int lane = tid & 63;
    const int wave = tid >> 6;
    const int quad = lane >> 4;
    const int l16 = lane & 15;
    const int m0 = bid * 64;
    const int colbase = wave * WC;

    f32x4 acc[4][NT];
#pragma unroll
    for (int rg = 0; rg < 4; rg++)
#pragma unroll
        for (int t = 0; t < NT; t++) acc[rg][t] = (f32x4){0.f, 0.f, 0.f, 0.f};

#pragma unroll
    for (int k0 = 0; k0 < K; k0 += 32) {
        half8 a[4];
#pragma unroll
        for (int rg = 0; rg < 4; rg++)
            a[rg] = *(const half8*)(sh + (rg * 16 + l16) * AS + k0 + quad * 8);
        half8 b[NT];
        const _Float16* Wk = Wt + (size_t)(k0 >> 5) * (NCOLT * 32);
#pragma unroll
        for (int t = 0; t < NT; t++)
            b[t] = *(const half8*)(Wk + (colbase + t * 16 + l16) * 32 + quad * 8);
#pragma unroll
        for (int rg = 0; rg < 4; rg++)
#pragma unroll
            for (int t = 0; t < NT; t++)
                acc[rg][t] = __builtin_amdgcn_mfma_f32_16x16x32_f16(b[t], a[rg], acc[rg][t], 0, 0, 0);
    }

    __syncthreads();  // done reading A-tile; reuse sh as C-tile

#pragma unroll
    for (int t = 0; t < NT; t++) {
        int c0 = colbase + t * 16 + quad * 4;
        f32x4 bv = {0.f, 0.f, 0.f, 0.f};
        if (c0 >= NCOL) bv = *(const f32x4*)(bias + (c0 - NCOL));
#pragma unroll
        for (int rg = 0; rg < 4; rg++) {
            half4 h = {(_Float16)(acc[rg][t][0] + bv[0]), (_Float16)(acc[rg][t][1] + bv[1]),
                       (_Float16)(acc[rg][t][2] + bv[2]), (_Float16)(acc[rg][t][3] + bv[3])};
            *(half4*)(sh + (rg * 16 + l16) * CS + c0) = h;
        }
    }
    __syncthreads();

#pragma unroll
    for (int i = 0; i < (64 * NCOL) / 2048; i++) {
        int off = i * 2048 + tid * 8;
        int row = off / NCOL, col = off % NCOL;
        if (m0 + row < M) {
            *(half8*)(Cl + (size_t)(m0 + row) * NCOL + col) = *(const half8*)(sh + row * CS + col);
            *(half8*)(Cr + (size_t)(m0 + row) * NCOL + col) = *(const half8*)(sh + row * CS + NCOL + col);
        }
    }
}

// gemm with global A staging (used by binGemm0 for layer 0, AF32 input)
template <int K, int NCOLT, bool AF32>
__device__ inline void gemm_body(const void* __restrict__ Av,
                                 const _Float16* __restrict__ Wt,
                                 const float* __restrict__ bias,
                                 _Float16* __restrict__ Cl,
                                 _Float16* __restrict__ Cr, int M, int bid,
                                 _Float16* __restrict__ sh) {
    constexpr int AS = K + 8;
    const int tid = threadIdx.x;
    const int m0 = bid * 64;

    if (AF32) {
        const float* A = (const float*)Av;
#pragma unroll
        for (int i = 0; i < K / 16; i++) {
            int off = i * 1024 + tid * 4;
            int row = off / K, col = off % K;
            f32x4 u = {0.f, 0.f, 0.f, 0.f};
            if (m0 + row < M) u = *(const f32x4*)(A + (size_t)(m0 + row) * K + col);
            half4 h = {(_Float16)u[0], (_Float16)u[1], (_Float16)u[2], (_Float16)u[3]};
            *(half4*)(sh + row * AS + col) = h;
        }
    } else {
        const _Float16* A = (const _Float16*)Av;
#pragma unroll
        for (int i = 0; i < K / 32; i++) {
            int off = i * 2048 + tid * 8;
            int row = off / K, col = off % K;
            half8 u = {0, 0, 0, 0, 0, 0, 0, 0};
            if (m0 + row < M) u = *(const half8*)(A + (size_t)(m0 + row) * K + col);
            *(half8*)(sh + row * AS + col) = u;
        }
    }
    __syncthreads();
    gemm_core<K, NCOLT>(sh, Wt, bias, Cl, Cr, M, bid);
}

// Fused: blocks [0,nbk) = edge binning; blocks [nbk, nbk+gGrid) = layer-0 GEMM.
__global__ __launch_bounds__(256) void k_binGemm0(
    const int* __restrict__ src, const int* __restrict__ dst,
    int* __restrict__ gcur, unsigned* __restrict__ ebuf, int E, int nbk,
    const float* __restrict__ x, const _Float16* __restrict__ Wt0,
    const float* __restrict__ b0, _Float16* __restrict__ xl,
    _Float16* __restrict__ xr, int M) {
    __shared__ __align__(16) char smem[64 * 264 * 2];  // max(gemm 33792B, bin 4096B)
    if ((int)blockIdx.x < nbk) {
        bin_body(src, dst, gcur, ebuf, E, blockIdx.x, (int*)smem);
    } else {
        gemm_body<256, 256, true>(x, Wt0, b0, xl, xr, M, blockIdx.x - nbk,
                                  (_Float16*)smem);
    }
}

// Fused per-bucket CSR finalize.
__global__ __launch_bounds__(256) void k_csr(const unsigned* __restrict__ ebuf,
                                             const int* __restrict__ bbase,
                                             int* __restrict__ rowptr,
                                             int* __restrict__ ssrc, int N) {
    __shared__ int cnt[256];
    __shared__ int sh[256];
    __shared__ int lc[256];
    const int t = threadIdx.x;
    const int b = blockIdx.x;
    cnt[t] = 0;
    __syncthreads();
    const int lo = bbase[b], hi = bbase[b + 1];
    for (int e = lo + t; e < hi; e += 256)
        atomicAdd(&cnt[ebuf[e] >> 24], 1);
    __syncthreads();
    const int myc = cnt[t];
    sh[t] = myc;
    __syncthreads();
    for (int off = 1; off < 256; off <<= 1) {
        int add = (t >= off) ? sh[t - off] : 0;
        __syncthreads();
        sh[t] += add;
        __syncthreads();
    }
    const int base = lo + (sh[t] - myc);   // bbase[b] + exclusive prefix
    const int n = (b << 8) + t;
    if (n <= N) rowptr[n] = base;          // n==N (last bucket) -> rowptr[N]=E
    lc[t] = base;
    __syncthreads();
    for (int e = lo + t; e < hi; e += 256) {
        unsigned v = ebuf[e];
        int pos = atomicAdd(&lc[v >> 24], 1);
        ssrc[pos] = (int)(v & 0xFFFFFFu);
    }
}

// ---------------- fused agg + next-layer GEMM ----------------
// Block = one 64-row GEMM tile. Two sequential agg sub-passes (32 nodes each,
// proven LPN=8 / 4-edge-unroll structure) write relu(res) f16 DIRECTLY into the
// GEMM A-tile in LDS -> h0/gb intermediates never touch HBM (saves 102 MB
// round trip). MODE 1 still stores the required f32 outputs (out1, g).

template <int NCOLT, int MODE>
__global__ __launch_bounds__(256) void k_aggGemm(
    const half8* __restrict__ xin_l, const half8* __restrict__ xin_r,
    const int* __restrict__ rowptr, const int* __restrict__ ssrc,
    float* __restrict__ outF1, float* __restrict__ outF2,
    const _Float16* __restrict__ Wt, const float* __restrict__ bias,
    _Float16* __restrict__ Cl, _Float16* __restrict__ Cr, int N) {
    constexpr int K = 128;
    constexpr int AS = K + 8;
    constexpr int MAXS = (NCOLT > K ? NCOLT : K) + 8;
    __shared__ _Float16 sh[64 * MAXS];

    const int tid = threadIdx.x;
    const int m0 = blockIdx.x * 64;
    const int c = tid & 7;          // lane-group channel slot (LPN=8)
    const int gidx = tid >> 3;      // node within sub-pass, 0..31
    const size_t cb = (size_t)c * 2;

#pragma unroll 1
    for (int sub = 0; sub < 2; sub++) {
        const int row = sub * 32 + gidx;
        const int n = m0 + row;
        half8 h0v = {0, 0, 0, 0, 0, 0, 0, 0};
        half8 h1v = {0, 0, 0, 0, 0, 0, 0, 0};
        if (n < N) {
            const int rp0 = rowptr[n];
            const int rp1 = rowptr[n + 1];
            float acc[16];
#pragma unroll
            for (int i = 0; i < 16; i++) acc[i] = 0.f;

            int e = rp0;
            for (; e + 3 < rp1; e += 4) {
                int s0 = ssrc[e], s1 = ssrc[e + 1], s2 = ssrc[e + 2], s3 = ssrc[e + 3];
                half8 v0a = xin_l[(size_t)s0 * 16 + cb], v0b = xin_l[(size_t)s0 * 16 + cb + 1];
                half8 v1a = xin_l[(size_t)s1 * 16 + cb], v1b = xin_l[(size_t)s1 * 16 + cb + 1];
                half8 v2a = xin_l[(size_t)s2 * 16 + cb], v2b = xin_l[(size_t)s2 * 16 + cb + 1];
                half8 v3a = xin_l[(size_t)s3 * 16 + cb], v3b = xin_l[(size_t)s3 * 16 + cb + 1];
#pragma unroll
                for (int i = 0; i < 8; i++) {
                    acc[i] += (float)v0a[i] + (float)v1a[i] + (float)v2a[i] + (float)v3a[i];
                    acc[8 + i] += (float)v0b[i] + (float)v1b[i] + (float)v2b[i] + (float)v3b[i];
                }
            }
            for (; e < rp1; e++) {
                int s = ssrc[e];
                half8 va = xin_l[(size_t)s * 16 + cb], vb = xin_l[(size_t)s * 16 + cb + 1];
#pragma unroll
                for (int i = 0; i < 8; i++) {
                    acc[i] += (float)va[i];
                    acc[8 + i] += (float)vb[i];
                }
            }

            const int deg = rp1 - rp0;
            const float scale = 1.0f / (float)(deg > 1 ? deg : 1);
            half8 x0 = xin_r[(size_t)n * 16 + cb];
            half8 x1 = xin_r[(size_t)n * 16 + cb + 1];
            float res[16];
#pragma unroll
            for (int i = 0; i < 8; i++) {
                res[i] = acc[i] * scale + (float)x0[i];
                res[8 + i] = acc[8 + i] * scale + (float)x1[i];
            }

            if (MODE == 1) {
                const size_t ob = (size_t)n * 128 + (size_t)c * 16;
#pragma unroll
                for (int q = 0; q < 4; q++) {
                    f32x4 v = {res[q * 4], res[q * 4 + 1], res[q * 4 + 2], res[q * 4 + 3]};
                    *(f32x4*)(outF1 + ob + q * 4) = v;
                    f32x4 z = {v[0] > 0.f ? v[0] : 0.f, v[1] > 0.f ? v[1] : 0.f,
                               v[2] > 0.f ? v[2] : 0.f, v[3] > 0.f ? v[3] : 0.f};
                    *(f32x4*)(outF2 + ob + q * 4) = z;
                }
            }
#pragma unroll
            for (int i = 0; i < 8; i++) {
                h0v[i] = (_Float16)(res[i] > 0.f ? res[i] : 0.f);
                h1v[i] = (_Float16)(res[8 + i] > 0.f ? res[8 + i] : 0.f);
            }
        }
        *(half8*)(sh + row * AS + c * 16) = h0v;
        *(half8*)(sh + row * AS + c * 16 + 8) = h1v;
    }
    __syncthreads();

    gemm_core<K, NCOLT>(sh, Wt, bias, Cl, Cr, N, blockIdx.x);
}

// ---------------- final aggregation (round-5 proven structure) ----------------

template <int COUT, int MODE>
__global__ __launch_bounds__(256) void k_agg(const half8* __restrict__ xl,
                                             const half8* __restrict__ xr,
                                             const int* __restrict__ rowptr,
                                             const int* __restrict__ ssrc,
                                             float* __restrict__ outF1,
                                             float* __restrict__ outF2,
                                             _Float16* __restrict__ outH, int N) {
    constexpr int LPN = COUT / 16;
    constexpr int NPB = 256 / LPN;
    constexpr int C8 = COUT / 8;
    const int tid = threadIdx.x;
    const int c = tid % LPN;
    const int n = blockIdx.x * NPB + tid / LPN;
    if (n >= N) return;

    const int rp0 = rowptr[n];
    const int rp1 = rowptr[n + 1];
    float acc[16];
#pragma unroll
    for (int i = 0; i < 16; i++) acc[i] = 0.f;

    const size_t cb = (size_t)c * 2;
    int e = rp0;
    for (; e + 3 < rp1; e += 4) {
        int s0 = ssrc[e], s1 = ssrc[e + 1], s2 = ssrc[e + 2], s3 = ssrc[e + 3];
        half8 v0a = xl[(size_t)s0 * C8 + cb], v0b = xl[(size_t)s0 * C8 + cb + 1];
        half8 v1a = xl[(size_t)s1 * C8 + cb], v1b = xl[(size_t)s1 * C8 + cb + 1];
        half8 v2a = xl[(size_t)s2 * C8 + cb], v2b = xl[(size_t)s2 * C8 + cb + 1];
        half8 v3a = xl[(size_t)s3 * C8 + cb], v3b = xl[(size_t)s3 * C8 + cb + 1];
#pragma unroll
        for (int i = 0; i < 8; i++) {
            acc[i] += (float)v0a[i] + (float)v1a[i] + (float)v2a[i] + (float)v3a[i];
            acc[8 + i] += (float)v0b[i] + (float)v1b[i] + (float)v2b[i] + (float)v3b[i];
        }
    }
    for (; e < rp1; e++) {
        int s = ssrc[e];
        half8 va = xl[(size_t)s * C8 + cb], vb = xl[(size_t)s * C8 + cb + 1];
#pragma unroll
        for (int i = 0; i < 8; i++) {
            acc[i] += (float)va[i];
            acc[8 + i] += (float)vb[i];
        }
    }

    const int deg = rp1 - rp0;
    const float scale = 1.0f / (float)(deg > 1 ? deg : 1);
    half8 x0 = xr[(size_t)n * C8 + cb];
    half8 x1 = xr[(size_t)n * C8 + cb + 1];
    float res[16];
#pragma unroll
    for (int i = 0; i < 8; i++) {
        res[i] = acc[i] * scale + (float)x0[i];
        res[8 + i] = acc[8 + i] * scale + (float)x1[i];
    }

    const size_t ob = (size_t)n * COUT + (size_t)c * 16;
    if (MODE == 2) {
#pragma unroll
        for (int q = 0; q < 4; q++) {
            f32x4 v = {res[q * 4], res[q * 4 + 1], res[q * 4 + 2], res[q * 4 + 3]};
            *(f32x4*)(outF1 + ob + q * 4) = v;
        }
    }
}

// ---------------- launch ----------------

extern "C" void kernel_launch(void* const* d_in, const int* in_sizes, int n_in,
                              void* d_out, int out_size, void* d_ws, size_t ws_size,
                              hipStream_t stream) {
    const float* x   = (const float*)d_in[0];
    const int*   ei  = (const int*)d_in[1];
    const float* Wl0 = (const float*)d_in[2];
    const float* Wr0 = (const float*)d_in[3];
    const float* b0  = (const float*)d_in[4];
    const float* Wl1 = (const float*)d_in[5];
    const float* Wr1 = (const float*)d_in[6];
    const float* b1  = (const float*)d_in[7];
    const float* Wl2 = (const float*)d_in[8];
    const float* Wr2 = (const float*)d_in[9];
    const float* b2  = (const float*)d_in[10];

    const int N = in_sizes[0] / 256;   // 100000
    const int E = in_sizes[1] / 2;     // 1600000
    const int* src = ei;
    const int* dst = ei + E;

    char* p = (char*)d_ws;
    auto alloc = [&](size_t bytes) -> void* {
        void* r = (void*)p;
        p += (bytes + 255) & ~(size_t)255;
        return r;
    };
    int*      rowptr   = (int*)alloc((size_t)(N + 1) * 4);
    int*      bcnt     = (int*)alloc(MAXB * 4);
    int*      bbase    = (int*)alloc((MAXB + 1) * 4);
    int*      gcur     = (int*)alloc(MAXB * 4);
    int*      ssrc     = (int*)alloc((size_t)E * 4);
    _Float16* xl       = (_Float16*)alloc((size_t)N * 128 * 2);
    _Float16* xr       = (_Float16*)alloc((size_t)N * 128 * 2);
    _Float16* xl2      = (_Float16*)alloc((size_t)N * 128 * 2);
    _Float16* xr2      = (_Float16*)alloc((size_t)N * 128 * 2);
    _Float16* Wt0      = (_Float16*)alloc((size_t)256 * 256 * 2);
    _Float16* Wt1      = (_Float16*)alloc((size_t)256 * 128 * 2);
    _Float16* Wt2      = (_Float16*)alloc((size_t)128 * 128 * 2);

    // ebuf (binned packed edges, E*4 B) aliases xl2: ebuf is dead after k_csr,
    // xl2 is first written by k_aggGemm<256,0> (later dispatch). Stream-ordered.
    unsigned* ebuf = (unsigned*)xl2;

    float* out = (float*)d_out;
    float* x_final = out;                      // N*64
    float* out1    = out + (size_t)N * 64;     // N*128
    float* g       = out + (size_t)N * 192;    // N*128

    const int nb = (N + 255) >> 8;
    const int nbk = (E + BIN_CHUNK - 1) / BIN_CHUNK;
    const int gGrid = (N + 63) / 64;

    // ---- CSR build overlapped with weight prep + layer-0 GEMM ----
    hipMemsetAsync(bcnt, 0, MAXB * 4, stream);
    k_bhistW<<<nbk + 448, 256, 0, stream>>>(dst, bcnt, E, nbk,
                                            Wl0, Wr0, Wl1, Wr1, Wl2, Wr2,
                                            Wt0, Wt1, Wt2);
    k_pscan<<<1, 512, 0, stream>>>(bcnt, bbase, gcur, bbase + nb, nb);
    k_binGemm0<<<nbk + gGrid, 256, 0, stream>>>(src, dst, gcur, ebuf, E, nbk,
                                                x, Wt0, b0, xl, xr, N);
    k_csr<<<nb, 256, 0, stream>>>(ebuf, bbase, rowptr, ssrc, N);

    // ---- layer 0 agg + layer 1 GEMM (h0 stays in LDS) ----
    k_aggGemm<256, 0><<<gGrid, 256, 0, stream>>>((const half8*)xl, (const half8*)xr,
                                                 rowptr, ssrc, nullptr, nullptr,
                                                 Wt1, b1, xl2, xr2, N);

    // ---- layer 1 agg + layer 2 GEMM (gb stays in LDS; out1/g stored) ----
    k_aggGemm<128, 1><<<gGrid, 256, 0, stream>>>((const half8*)xl2, (const half8*)xr2,
                                                 rowptr, ssrc, out1, g,
                                                 Wt2, b2, xl, xr, N);

    // ---- final aggregation ----
    k_agg<64, 2><<<(N + 63) / 64, 256, 0, stream>>>((const half8*)xl, (const half8*)xr,
                                                    rowptr, ssrc, x_final, nullptr, nullptr, N);
}